// Round 1
// baseline (433.982 us; speedup 1.0000x reference)
//
#include <hip/hip_runtime.h>
#include <hip/hip_bf16.h>

typedef unsigned short u16;
typedef __attribute__((ext_vector_type(4))) float f32x4;
typedef __attribute__((ext_vector_type(8))) short short8;  // 8 bf16 raw bits

#define B_ 2
#define T_ 256
#define D_ 2048
#define H_ 32
#define HS_ 64
#define M_ 512          // B*T
#define ST_ 66
#define EPS_ 1e-5f

__device__ __forceinline__ float bf2f(u16 u) {
    union { unsigned int i; float f; } c; c.i = ((unsigned int)u) << 16; return c.f;
}
__device__ __forceinline__ u16 f2bf(float f) {
    union { unsigned int i; float f; } c; c.f = f;
    unsigned int r = c.i + 0x7fffu + ((c.i >> 16) & 1u);   // round-to-nearest-even
    return (u16)(r >> 16);
}

// ---------------- LayerNorm: x -> xln ----------------
__global__ __launch_bounds__(256) void ln_kernel(const float* __restrict__ x, const float* __restrict__ w,
                                                 const float* __restrict__ bias, float* __restrict__ xln)
{
    const int row = blockIdx.x;                 // 0..511
    const float* xr = x + (size_t)row * D_;
    float* orow = xln + (size_t)row * D_;
    const int t = threadIdx.x;
    f32x4 a0 = *(const f32x4*)(xr + t * 8);
    f32x4 a1 = *(const f32x4*)(xr + t * 8 + 4);
    float s = 0.f, q = 0.f;
#pragma unroll
    for (int i = 0; i < 4; i++) { s += a0[i] + a1[i]; q += a0[i]*a0[i] + a1[i]*a1[i]; }
#pragma unroll
    for (int off = 1; off < 64; off <<= 1) { s += __shfl_xor(s, off, 64); q += __shfl_xor(q, off, 64); }
    __shared__ float ls[4], lq[4];
    const int wid = t >> 6, lane = t & 63;
    if (lane == 0) { ls[wid] = s; lq[wid] = q; }
    __syncthreads();
    s = ls[0] + ls[1] + ls[2] + ls[3];
    q = lq[0] + lq[1] + lq[2] + lq[3];
    const float mu = s * (1.f / D_);
    const float var = q * (1.f / D_) - mu * mu;
    const float rs = rsqrtf(var + EPS_);
#pragma unroll
    for (int i = 0; i < 8; i++) {
        int d = t * 8 + i;
        float f = (i < 4) ? a0[i] : a1[i - 4];
        orow[d] = (f - mu) * rs * w[d] + bias[d];
    }
}

// ---------------- token shift: sx = prev - cur ; xxx = xln + sx*maa_x ----------------
__global__ __launch_bounds__(256) void shift_kernel(const float* __restrict__ xln, const float* __restrict__ state,
                                                    const float* __restrict__ maax, const int* __restrict__ ip,
                                                    float* __restrict__ sx, float* __restrict__ xxx)
{
    const size_t gid = (size_t)blockIdx.x * 256 + threadIdx.x;
    const size_t e = gid * 4;                   // 4 floats per thread
    const int row = (int)(e >> 11);
    const int d = (int)(e & 2047);
    const int tt = row & (T_ - 1);
    const int b = row >> 8;
    const float* prev;
    if (tt == 0) prev = state + ((size_t)b * ST_ + (size_t)(66 * ip[0] + 1)) * D_ + d;
    else         prev = xln + e - D_;
    f32x4 p = *(const f32x4*)prev;
    f32x4 c = *(const f32x4*)(xln + e);
    f32x4 mx = *(const f32x4*)(maax + d);
    f32x4 sv, xv;
#pragma unroll
    for (int i = 0; i < 4; i++) { sv[i] = p[i] - c[i]; xv[i] = c[i] + sv[i] * mx[i]; }
    *(f32x4*)(sx + e) = sv;
    *(f32x4*)(xxx + e) = xv;
}

// ---------------- maa lora stage 1: t5 = tanh(xxx @ w1)   [512][160] ----------------
__global__ __launch_bounds__(256) void maa1_kernel(const float* __restrict__ xxx, const float* __restrict__ w1,
                                                   float* __restrict__ t5)
{
    const int gid = blockIdx.x * 256 + threadIdx.x;   // < 81920
    const int m = gid / 160, n = gid - m * 160;
    const float* xr = xxx + (size_t)m * D_;
    const float* wp = w1 + n;
    float acc = 0.f;
    for (int k = 0; k < D_; k += 8) {
        f32x4 x0 = *(const f32x4*)(xr + k);
        f32x4 x1 = *(const f32x4*)(xr + k + 4);
#pragma unroll
        for (int j = 0; j < 4; j++) {
            acc = fmaf(x0[j], wp[(size_t)(k + j) * 160], acc);
            acc = fmaf(x1[j], wp[(size_t)(k + 4 + j) * 160], acc);
        }
    }
    t5[gid] = tanhf(acc);
}

// ---------------- maa lora stage 2 + x5 build (bf16) ----------------
// x5[f][m][d] = xln + sx*(maa_f + sum_r t5[m,f,r]*w2[f,r,d]) ; 4 m-rows per thread
__global__ __launch_bounds__(256) void maa2_kernel(const float* __restrict__ t5, const float* __restrict__ w2,
                                                   const float* __restrict__ xln, const float* __restrict__ sxp,
                                                   const float* __restrict__ mk, const float* __restrict__ mw,
                                                   const float* __restrict__ mv, const float* __restrict__ mr,
                                                   const float* __restrict__ mg, u16* __restrict__ x5)
{
    const int gid = blockIdx.x * 256 + threadIdx.x;   // 5*2048*128
    const int d = gid & (D_ - 1);
    const int f = (gid >> 11) % 5;
    const int mg4 = gid / (5 * D_);                   // 0..127
    const float* maa = (f == 0) ? mk : (f == 1) ? mw : (f == 2) ? mv : (f == 3) ? mr : mg;
    const float mf = maa[d];
    const float* w2f = w2 + (size_t)f * 32 * D_ + d;
    const float* t5b = t5 + (size_t)mg4 * 4 * 160 + f * 32;
    float a0 = 0, a1 = 0, a2 = 0, a3 = 0;
#pragma unroll 8
    for (int r = 0; r < 32; r++) {
        float wv = w2f[(size_t)r * D_];
        a0 = fmaf(t5b[r], wv, a0);
        a1 = fmaf(t5b[160 + r], wv, a1);
        a2 = fmaf(t5b[320 + r], wv, a2);
        a3 = fmaf(t5b[480 + r], wv, a3);
    }
    const float accs[4] = {a0, a1, a2, a3};
    const size_t m0 = (size_t)mg4 * 4;
#pragma unroll
    for (int mm = 0; mm < 4; mm++) {
        size_t e = (m0 + mm) * D_ + d;
        x5[(size_t)f * M_ * D_ + e] = f2bf(xln[e] + sxp[e] * (mf + accs[mm]));
    }
}

// ---------------- decay lora stage 1: td = tanh(x5[1] @ dw1)  [512][64] ----------------
__global__ __launch_bounds__(256) void decay1_kernel(const u16* __restrict__ x5, const float* __restrict__ dw1,
                                                     float* __restrict__ td)
{
    const int gid = blockIdx.x * 256 + threadIdx.x;   // 32768
    const int n = gid & 63, m = gid >> 6;
    const u16* xr = x5 + (size_t)(M_ + m) * D_;       // f = 1 slice
    const float* wp = dw1 + n;
    float acc = 0.f;
    for (int k = 0; k < D_; k += 8) {
        short8 xv = *(const short8*)(xr + k);
#pragma unroll
        for (int j = 0; j < 8; j++) acc = fmaf(bf2f((u16)xv[j]), wp[(size_t)(k + j) * 64], acc);
    }
    td[gid] = tanhf(acc);
}

// ---------------- decay lora stage 2: w = exp(-exp(time_decay + td @ dw2)) ----------------
__global__ __launch_bounds__(256) void decay2_kernel(const float* __restrict__ td, const float* __restrict__ dw2,
                                                     const float* __restrict__ tdec, float* __restrict__ wout)
{
    const int gid = blockIdx.x * 256 + threadIdx.x;   // 2048*128
    const int d = gid & (D_ - 1);
    const int mg4 = gid >> 11;                        // 0..127
    const float* wp = dw2 + d;
    const float* tb = td + (size_t)mg4 * 4 * 64;
    float a0 = 0, a1 = 0, a2 = 0, a3 = 0;
#pragma unroll 8
    for (int r = 0; r < 64; r++) {
        float wv = wp[(size_t)r * D_];
        a0 = fmaf(tb[r], wv, a0);
        a1 = fmaf(tb[64 + r], wv, a1);
        a2 = fmaf(tb[128 + r], wv, a2);
        a3 = fmaf(tb[192 + r], wv, a3);
    }
    const float base = tdec[d];
    const float accs[4] = {a0, a1, a2, a3};
#pragma unroll
    for (int mm = 0; mm < 4; mm++)
        wout[((size_t)mg4 * 4 + mm) * D_ + d] = expf(-expf(base + accs[mm]));
}

// ---------------- bf16 MFMA GEMM:  C[m,n] = sum_k A[m,k] * W[n,k]  (A bf16, W f32->bf16) ----------------
__device__ __forceinline__ void gemm_body(const u16* __restrict__ A, const float* __restrict__ W,
                                          float* __restrict__ C)
{
    __shared__ u16 As[128 * 32];
    __shared__ u16 Bs[128 * 32];
    const int tid = threadIdx.x;
    const int m0 = blockIdx.y * 128;
    const int n0 = blockIdx.x * 128;
    const int lane = tid & 63;
    const int wid = tid >> 6;
    const int wm = (wid >> 1) * 64;
    const int wn = (wid & 1) * 64;

    f32x4 acc[4][4];
#pragma unroll
    for (int i = 0; i < 4; i++)
#pragma unroll
        for (int j = 0; j < 4; j++) { acc[i][j][0] = 0.f; acc[i][j][1] = 0.f; acc[i][j][2] = 0.f; acc[i][j][3] = 0.f; }

    const int rA = tid >> 2;            // 0..63
    const int kA = (tid & 3) * 8;       // 0,8,16,24
    const u16* gA0 = A + (size_t)(m0 + rA) * D_ + kA;
    const u16* gA1 = A + (size_t)(m0 + rA + 64) * D_ + kA;
    const float* gW0 = W + (size_t)(n0 + rA) * D_ + kA;
    const float* gW1 = W + (size_t)(n0 + rA + 64) * D_ + kA;
    u16* lA0 = As + tid * 8;
    u16* lA1 = As + (tid + 256) * 8;
    u16* lB0 = Bs + tid * 8;
    u16* lB1 = Bs + (tid + 256) * 8;

    const u16* pa = As + (size_t)(wm + (lane & 15)) * 32 + (lane >> 4) * 8;
    const u16* pb = Bs + (size_t)(wn + (lane & 15)) * 32 + (lane >> 4) * 8;

    for (int kt = 0; kt < D_; kt += 32) {
        short8 a0 = *(const short8*)(gA0 + kt);
        short8 a1 = *(const short8*)(gA1 + kt);
        f32x4 w00 = *(const f32x4*)(gW0 + kt);
        f32x4 w01 = *(const f32x4*)(gW0 + kt + 4);
        f32x4 w10 = *(const f32x4*)(gW1 + kt);
        f32x4 w11 = *(const f32x4*)(gW1 + kt + 4);
        __syncthreads();                 // everyone done reading previous tile
        *(short8*)lA0 = a0;
        *(short8*)lA1 = a1;
        short8 sb0, sb1;
#pragma unroll
        for (int j = 0; j < 4; j++) {
            sb0[j]     = (short)f2bf(w00[j]);
            sb0[j + 4] = (short)f2bf(w01[j]);
            sb1[j]     = (short)f2bf(w10[j]);
            sb1[j + 4] = (short)f2bf(w11[j]);
        }
        *(short8*)lB0 = sb0;
        *(short8*)lB1 = sb1;
        __syncthreads();                 // tile visible
        short8 av[4], bv[4];
#pragma unroll
        for (int mi = 0; mi < 4; mi++) av[mi] = *(const short8*)(pa + mi * 16 * 32);
#pragma unroll
        for (int ni = 0; ni < 4; ni++) bv[ni] = *(const short8*)(pb + ni * 16 * 32);
#pragma unroll
        for (int mi = 0; mi < 4; mi++)
#pragma unroll
            for (int ni = 0; ni < 4; ni++)
                acc[mi][ni] = __builtin_amdgcn_mfma_f32_16x16x32_bf16(av[mi], bv[ni], acc[mi][ni], 0, 0, 0);
    }
    // epilogue: C/D layout col=lane&15, row=(lane>>4)*4+reg
    const int cr = wm + (lane >> 4) * 4;
    const int cc = wn + (lane & 15);
#pragma unroll
    for (int mi = 0; mi < 4; mi++)
#pragma unroll
        for (int ni = 0; ni < 4; ni++)
#pragma unroll
            for (int j = 0; j < 4; j++)
                C[(size_t)(m0 + cr + mi * 16 + j) * D_ + (n0 + cc + ni * 16)] = acc[mi][ni][j];
}

__global__ __launch_bounds__(256) void gemm4_kernel(const u16* __restrict__ x5, const float* __restrict__ Wk,
                                                    const float* __restrict__ Wv, const float* __restrict__ Wr,
                                                    const float* __restrict__ Wg, float* __restrict__ kvrg)
{
    const int mm = blockIdx.z;   // 0:k(x5[0]) 1:v(x5[2]) 2:r(x5[3]) 3:g(x5[4])
    const u16* A = x5 + (size_t)(mm == 0 ? 0 : mm + 1) * M_ * D_;
    const float* W = (mm == 0) ? Wk : (mm == 1) ? Wv : (mm == 2) ? Wr : Wg;
    float* C = kvrg + (size_t)mm * M_ * D_;
    gemm_body(A, W, C);
}

__global__ __launch_bounds__(256) void gemm1_kernel(const u16* __restrict__ y, const float* __restrict__ Wo,
                                                    float* __restrict__ out)
{
    gemm_body(y, Wo, out);
}

// ---------------- sequential recurrence over T ----------------
// one block per (b,h); lane: jb = lane>>3 (8 j's each), dsub = lane&7; wave wv: d = wv*8+dsub and +32
__global__ __launch_bounds__(256) void rec_kernel(const float* __restrict__ rB, const float* __restrict__ kB,
                                                  const float* __restrict__ wB, const float* __restrict__ vB,
                                                  const float* __restrict__ fa, const float* __restrict__ state,
                                                  const int* __restrict__ ip, float* __restrict__ rwkv)
{
    const int bh = blockIdx.x;
    const int b = bh >> 5, h = bh & 31;
    const int tid = threadIdx.x;
    const int wv = tid >> 6, lane = tid & 63;
    const int jb = lane >> 3, dsub = lane & 7;
    const int d0 = wv * 8 + dsub;
    const int jbase = jb * 8;

    __shared__ float stage[2][4][64];     // [buf][r,k,w,v][64]

    float S0v[8], S1v[8], faj[8];
    {
        const float* Sp = state + (size_t)b * ST_ * D_ + (size_t)(66 * ip[0] + 2) * D_ + (size_t)h * HS_ * HS_;
#pragma unroll
        for (int jj = 0; jj < 8; jj++) {
            S0v[jj] = Sp[(jbase + jj) * 64 + d0];
            S1v[jj] = Sp[(jbase + jj) * 64 + d0 + 32];
            faj[jj] = fa[h * 64 + jbase + jj];
        }
    }
    const size_t base = ((size_t)b * T_ * H_ + h) * HS_;
    const float* mysrc = (wv == 0) ? rB : (wv == 1) ? kB : (wv == 2) ? wB : vB;

    stage[0][wv][lane] = mysrc[base + lane];
    __syncthreads();

    for (int t = 0; t < T_; t++) {
        const int cur = t & 1;
        if (t + 1 < T_)   // prefetch next timestep into other buffer (prev reads of it fenced by last barrier)
            stage[cur ^ 1][wv][lane] = mysrc[base + (size_t)(t + 1) * (H_ * HS_) + lane];

        float rj[8], kj[8], wj[8];
        *(f32x4*)&rj[0] = *(const f32x4*)&stage[cur][0][jbase];
        *(f32x4*)&rj[4] = *(const f32x4*)&stage[cur][0][jbase + 4];
        *(f32x4*)&kj[0] = *(const f32x4*)&stage[cur][1][jbase];
        *(f32x4*)&kj[4] = *(const f32x4*)&stage[cur][1][jbase + 4];
        *(f32x4*)&wj[0] = *(const f32x4*)&stage[cur][2][jbase];
        *(f32x4*)&wj[4] = *(const f32x4*)&stage[cur][2][jbase + 4];
        const float vd0 = stage[cur][3][d0];
        const float vd1 = stage[cur][3][d0 + 32];

        float s1 = 0.f, s2a = 0.f, s2b = 0.f;
#pragma unroll
        for (int jj = 0; jj < 8; jj++) {
            float rf = rj[jj] * faj[jj];
            s1  = fmaf(rf, kj[jj], s1);
            s2a = fmaf(rj[jj], S0v[jj], s2a);
            s2b = fmaf(rj[jj], S1v[jj], s2b);
        }
#pragma unroll
        for (int off = 8; off <= 32; off <<= 1) {
            s1  += __shfl_xor(s1, off, 64);
            s2a += __shfl_xor(s2a, off, 64);
            s2b += __shfl_xor(s2b, off, 64);
        }
        if (jb == 0) {
            float* o = rwkv + base + (size_t)t * (H_ * HS_);
            o[d0]      = fmaf(vd0, s1, s2a);
            o[d0 + 32] = fmaf(vd1, s1, s2b);
        }
#pragma unroll
        for (int jj = 0; jj < 8; jj++) {
            S0v[jj] = fmaf(wj[jj], S0v[jj], kj[jj] * vd0);
            S1v[jj] = fmaf(wj[jj], S1v[jj], kj[jj] * vd1);
        }
        __syncthreads();
    }
}

// ---------------- groupnorm + gate: y = (gn(rwkv)*lnxw+lnxb) * silu(gpre), bf16 ----------------
__global__ __launch_bounds__(256) void gn_kernel(const float* __restrict__ rwkv, const float* __restrict__ gpre,
                                                 const float* __restrict__ lnxw, const float* __restrict__ lnxb,
                                                 u16* __restrict__ y)
{
    const int g = blockIdx.x * 4 + (threadIdx.x >> 6);   // (b*T+t)*H + h
    const int lane = threadIdx.x & 63;
    const size_t e = (size_t)g * 64 + lane;
    const float val = rwkv[e];
    float s = val, q = val * val;
#pragma unroll
    for (int off = 1; off < 64; off <<= 1) { s += __shfl_xor(s, off, 64); q += __shfl_xor(q, off, 64); }
    const float mu = s * (1.f / 64.f);
    const float var = q * (1.f / 64.f) - mu * mu;
    const float rs = rsqrtf(var + EPS_);
    const int hj = (int)(e & (size_t)(D_ - 1));
    const float nrm = (val - mu) * rs * lnxw[hj] + lnxb[hj];
    const float gp = gpre[e];
    const float gv = gp / (1.f + expf(-gp));
    y[e] = f2bf(nrm * gv);
}

extern "C" void kernel_launch(void* const* d_in, const int* in_sizes, int n_in,
                              void* d_out, int out_size, void* d_ws, size_t ws_size,
                              hipStream_t stream)
{
    const float* x     = (const float*)d_in[0];
    const float* state = (const float*)d_in[1];
    const float* ln1w  = (const float*)d_in[2];
    const float* ln1b  = (const float*)d_in[3];
    const float* maax  = (const float*)d_in[4];
    const float* w1    = (const float*)d_in[5];
    const float* w2    = (const float*)d_in[6];
    const float* maak  = (const float*)d_in[7];
    const float* maaw  = (const float*)d_in[8];
    const float* maav  = (const float*)d_in[9];
    const float* maar  = (const float*)d_in[10];
    const float* maag  = (const float*)d_in[11];
    const float* tdec  = (const float*)d_in[12];
    const float* dw1   = (const float*)d_in[13];
    const float* dw2   = (const float*)d_in[14];
    const float* fa    = (const float*)d_in[15];
    const float* wrec  = (const float*)d_in[16];
    const float* wkey  = (const float*)d_in[17];
    const float* wval  = (const float*)d_in[18];
    const float* wout  = (const float*)d_in[19];
    const float* wgate = (const float*)d_in[20];
    const float* lnxw  = (const float*)d_in[21];
    const float* lnxb  = (const float*)d_in[22];
    const int*   ip    = (const int*)d_in[23];

    char* ws = (char*)d_ws;
    const size_t MD = (size_t)M_ * D_;
    float* xln  = (float*)(ws);
    float* sx   = (float*)(ws + ((size_t)4  << 20));
    float* xxx  = (float*)(ws + ((size_t)8  << 20));
    float* t5   = (float*)(ws + ((size_t)12 << 20));
    u16*   x5   = (u16*)  (ws + ((size_t)13 << 20));
    float* td   = (float*)(ws + ((size_t)23 << 20));
    float* wdec = (float*)(ws + ((size_t)24 << 20));
    float* kvrg = (float*)(ws + ((size_t)28 << 20));
    float* rwkv = (float*)(ws + ((size_t)44 << 20));
    u16*   y    = (u16*)  (ws + ((size_t)48 << 20));
    float* out  = (float*)d_out;

    hipLaunchKernelGGL(ln_kernel,     dim3(512),      dim3(256), 0, stream, x, ln1w, ln1b, xln);
    hipLaunchKernelGGL(shift_kernel,  dim3(1024),     dim3(256), 0, stream, xln, state, maax, ip, sx, xxx);
    hipLaunchKernelGGL(maa1_kernel,   dim3(320),      dim3(256), 0, stream, xxx, w1, t5);
    hipLaunchKernelGGL(maa2_kernel,   dim3(5120),     dim3(256), 0, stream, t5, w2, xln, sx, maak, maaw, maav, maar, maag, x5);
    hipLaunchKernelGGL(decay1_kernel, dim3(128),      dim3(256), 0, stream, x5, dw1, td);
    hipLaunchKernelGGL(decay2_kernel, dim3(1024),     dim3(256), 0, stream, td, dw2, tdec, wdec);
    hipLaunchKernelGGL(gemm4_kernel,  dim3(16, 4, 4), dim3(256), 0, stream, x5, wkey, wval, wrec, wgate, kvrg);
    hipLaunchKernelGGL(rec_kernel,    dim3(64),       dim3(256), 0, stream, kvrg + 2 * MD, kvrg, wdec, kvrg + MD, fa, state, ip, rwkv);
    hipLaunchKernelGGL(gn_kernel,     dim3(4096),     dim3(256), 0, stream, rwkv, kvrg + 3 * MD, lnxw, lnxb, y);
    hipLaunchKernelGGL(gemm1_kernel,  dim3(16, 4, 1), dim3(256), 0, stream, y, wout, out);

    (void)in_sizes; (void)n_in; (void)out_size; (void)ws_size;
}

// Round 2
// 366.987 us; speedup vs baseline: 1.1826x; 1.1826x over previous
//
#include <hip/hip_runtime.h>
#include <hip/hip_bf16.h>

typedef unsigned short u16;
typedef __attribute__((ext_vector_type(4))) float f32x4;
typedef __attribute__((ext_vector_type(8))) short short8;  // 8 bf16 raw bits

#define B_ 2
#define T_ 256
#define D_ 2048
#define H_ 32
#define HS_ 64
#define M_ 512          // B*T
#define ST_ 66
#define EPS_ 1e-5f

__device__ __forceinline__ float bf2f(u16 u) {
    union { unsigned int i; float f; } c; c.i = ((unsigned int)u) << 16; return c.f;
}
__device__ __forceinline__ u16 f2bf(float f) {
    union { unsigned int i; float f; } c; c.f = f;
    unsigned int r = c.i + 0x7fffu + ((c.i >> 16) & 1u);   // round-to-nearest-even
    return (u16)(r >> 16);
}

// ---------------- LayerNorm: x -> xln ----------------
__global__ __launch_bounds__(256) void ln_kernel(const float* __restrict__ x, const float* __restrict__ w,
                                                 const float* __restrict__ bias, float* __restrict__ xln)
{
    const int row = blockIdx.x;                 // 0..511
    const float* xr = x + (size_t)row * D_;
    float* orow = xln + (size_t)row * D_;
    const int t = threadIdx.x;
    f32x4 a0 = *(const f32x4*)(xr + t * 8);
    f32x4 a1 = *(const f32x4*)(xr + t * 8 + 4);
    float s = 0.f, q = 0.f;
#pragma unroll
    for (int i = 0; i < 4; i++) { s += a0[i] + a1[i]; q += a0[i]*a0[i] + a1[i]*a1[i]; }
#pragma unroll
    for (int off = 1; off < 64; off <<= 1) { s += __shfl_xor(s, off, 64); q += __shfl_xor(q, off, 64); }
    __shared__ float ls[4], lq[4];
    const int wid = t >> 6, lane = t & 63;
    if (lane == 0) { ls[wid] = s; lq[wid] = q; }
    __syncthreads();
    s = ls[0] + ls[1] + ls[2] + ls[3];
    q = lq[0] + lq[1] + lq[2] + lq[3];
    const float mu = s * (1.f / D_);
    const float var = q * (1.f / D_) - mu * mu;
    const float rs = rsqrtf(var + EPS_);
#pragma unroll
    for (int i = 0; i < 8; i++) {
        int d = t * 8 + i;
        float f = (i < 4) ? a0[i] : a1[i - 4];
        orow[d] = (f - mu) * rs * w[d] + bias[d];
    }
}

// ---------------- token shift: sx = prev - cur ; xxx = xln + sx*maa_x ----------------
__global__ __launch_bounds__(256) void shift_kernel(const float* __restrict__ xln, const float* __restrict__ state,
                                                    const float* __restrict__ maax, const int* __restrict__ ip,
                                                    float* __restrict__ sx, float* __restrict__ xxx)
{
    const size_t gid = (size_t)blockIdx.x * 256 + threadIdx.x;
    const size_t e = gid * 4;                   // 4 floats per thread
    const int row = (int)(e >> 11);
    const int d = (int)(e & 2047);
    const int tt = row & (T_ - 1);
    const int b = row >> 8;
    const float* prev;
    if (tt == 0) prev = state + ((size_t)b * ST_ + (size_t)(66 * ip[0] + 1)) * D_ + d;
    else         prev = xln + e - D_;
    f32x4 p = *(const f32x4*)prev;
    f32x4 c = *(const f32x4*)(xln + e);
    f32x4 mx = *(const f32x4*)(maax + d);
    f32x4 sv, xv;
#pragma unroll
    for (int i = 0; i < 4; i++) { sv[i] = p[i] - c[i]; xv[i] = c[i] + sv[i] * mx[i]; }
    *(f32x4*)(sx + e) = sv;
    *(f32x4*)(xxx + e) = xv;
}

// ---------------- maa lora stage 1: t5 = tanh(xxx @ w1)   [512][160] ----------------
__global__ __launch_bounds__(256) void maa1_kernel(const float* __restrict__ xxx, const float* __restrict__ w1,
                                                   float* __restrict__ t5)
{
    const int gid = blockIdx.x * 256 + threadIdx.x;   // < 81920
    const int m = gid / 160, n = gid - m * 160;
    const float* xr = xxx + (size_t)m * D_;
    const float* wp = w1 + n;
    float acc = 0.f;
    for (int k = 0; k < D_; k += 8) {
        f32x4 x0 = *(const f32x4*)(xr + k);
        f32x4 x1 = *(const f32x4*)(xr + k + 4);
#pragma unroll
        for (int j = 0; j < 4; j++) {
            acc = fmaf(x0[j], wp[(size_t)(k + j) * 160], acc);
            acc = fmaf(x1[j], wp[(size_t)(k + 4 + j) * 160], acc);
        }
    }
    t5[gid] = tanhf(acc);
}

// ---------------- maa lora stage 2 + x5 build (bf16) ----------------
__global__ __launch_bounds__(256) void maa2_kernel(const float* __restrict__ t5, const float* __restrict__ w2,
                                                   const float* __restrict__ xln, const float* __restrict__ sxp,
                                                   const float* __restrict__ mk, const float* __restrict__ mw,
                                                   const float* __restrict__ mv, const float* __restrict__ mr,
                                                   const float* __restrict__ mg, u16* __restrict__ x5)
{
    const int gid = blockIdx.x * 256 + threadIdx.x;   // 5*2048*128
    const int d = gid & (D_ - 1);
    const int f = (gid >> 11) % 5;
    const int mg4 = gid / (5 * D_);                   // 0..127
    const float* maa = (f == 0) ? mk : (f == 1) ? mw : (f == 2) ? mv : (f == 3) ? mr : mg;
    const float mf = maa[d];
    const float* w2f = w2 + (size_t)f * 32 * D_ + d;
    const float* t5b = t5 + (size_t)mg4 * 4 * 160 + f * 32;
    float a0 = 0, a1 = 0, a2 = 0, a3 = 0;
#pragma unroll 8
    for (int r = 0; r < 32; r++) {
        float wv = w2f[(size_t)r * D_];
        a0 = fmaf(t5b[r], wv, a0);
        a1 = fmaf(t5b[160 + r], wv, a1);
        a2 = fmaf(t5b[320 + r], wv, a2);
        a3 = fmaf(t5b[480 + r], wv, a3);
    }
    const float accs[4] = {a0, a1, a2, a3};
    const size_t m0 = (size_t)mg4 * 4;
#pragma unroll
    for (int mm = 0; mm < 4; mm++) {
        size_t e = (m0 + mm) * D_ + d;
        x5[(size_t)f * M_ * D_ + e] = f2bf(xln[e] + sxp[e] * (mf + accs[mm]));
    }
}

// ---------------- decay lora stage 1: td = tanh(x5[1] @ dw1)  [512][64] ----------------
__global__ __launch_bounds__(256) void decay1_kernel(const u16* __restrict__ x5, const float* __restrict__ dw1,
                                                     float* __restrict__ td)
{
    const int gid = blockIdx.x * 256 + threadIdx.x;   // 32768
    const int n = gid & 63, m = gid >> 6;
    const u16* xr = x5 + (size_t)(M_ + m) * D_;       // f = 1 slice
    const float* wp = dw1 + n;
    float acc = 0.f;
    for (int k = 0; k < D_; k += 8) {
        short8 xv = *(const short8*)(xr + k);
#pragma unroll
        for (int j = 0; j < 8; j++) acc = fmaf(bf2f((u16)xv[j]), wp[(size_t)(k + j) * 64], acc);
    }
    td[gid] = tanhf(acc);
}

// ---------------- decay lora stage 2: w = exp(-exp(time_decay + td @ dw2)) ----------------
__global__ __launch_bounds__(256) void decay2_kernel(const float* __restrict__ td, const float* __restrict__ dw2,
                                                     const float* __restrict__ tdec, float* __restrict__ wout)
{
    const int gid = blockIdx.x * 256 + threadIdx.x;   // 2048*128
    const int d = gid & (D_ - 1);
    const int mg4 = gid >> 11;                        // 0..127
    const float* wp = dw2 + d;
    const float* tb = td + (size_t)mg4 * 4 * 64;
    float a0 = 0, a1 = 0, a2 = 0, a3 = 0;
#pragma unroll 8
    for (int r = 0; r < 64; r++) {
        float wv = wp[(size_t)r * D_];
        a0 = fmaf(tb[r], wv, a0);
        a1 = fmaf(tb[64 + r], wv, a1);
        a2 = fmaf(tb[128 + r], wv, a2);
        a3 = fmaf(tb[192 + r], wv, a3);
    }
    const float base = tdec[d];
    const float accs[4] = {a0, a1, a2, a3};
#pragma unroll
    for (int mm = 0; mm < 4; mm++)
        wout[((size_t)mg4 * 4 + mm) * D_ + d] = expf(-expf(base + accs[mm]));
}

// ---------------- bf16 MFMA GEMM:  C[m,n] = sum_k A[m,k] * W[n,k]  (A bf16, W f32->bf16) ----------------
__device__ __forceinline__ void gemm_body(const u16* __restrict__ A, const float* __restrict__ W,
                                          float* __restrict__ C)
{
    __shared__ u16 As[128 * 32];
    __shared__ u16 Bs[128 * 32];
    const int tid = threadIdx.x;
    const int m0 = blockIdx.y * 128;
    const int n0 = blockIdx.x * 128;
    const int lane = tid & 63;
    const int wid = tid >> 6;
    const int wm = (wid >> 1) * 64;
    const int wn = (wid & 1) * 64;

    f32x4 acc[4][4];
#pragma unroll
    for (int i = 0; i < 4; i++)
#pragma unroll
        for (int j = 0; j < 4; j++) { acc[i][j][0] = 0.f; acc[i][j][1] = 0.f; acc[i][j][2] = 0.f; acc[i][j][3] = 0.f; }

    const int rA = tid >> 2;            // 0..63
    const int kA = (tid & 3) * 8;       // 0,8,16,24
    const u16* gA0 = A + (size_t)(m0 + rA) * D_ + kA;
    const u16* gA1 = A + (size_t)(m0 + rA + 64) * D_ + kA;
    const float* gW0 = W + (size_t)(n0 + rA) * D_ + kA;
    const float* gW1 = W + (size_t)(n0 + rA + 64) * D_ + kA;
    u16* lA0 = As + tid * 8;
    u16* lA1 = As + (tid + 256) * 8;
    u16* lB0 = Bs + tid * 8;
    u16* lB1 = Bs + (tid + 256) * 8;

    const u16* pa = As + (size_t)(wm + (lane & 15)) * 32 + (lane >> 4) * 8;
    const u16* pb = Bs + (size_t)(wn + (lane & 15)) * 32 + (lane >> 4) * 8;

    for (int kt = 0; kt < D_; kt += 32) {
        short8 a0 = *(const short8*)(gA0 + kt);
        short8 a1 = *(const short8*)(gA1 + kt);
        f32x4 w00 = *(const f32x4*)(gW0 + kt);
        f32x4 w01 = *(const f32x4*)(gW0 + kt + 4);
        f32x4 w10 = *(const f32x4*)(gW1 + kt);
        f32x4 w11 = *(const f32x4*)(gW1 + kt + 4);
        __syncthreads();                 // everyone done reading previous tile
        *(short8*)lA0 = a0;
        *(short8*)lA1 = a1;
        short8 sb0, sb1;
#pragma unroll
        for (int j = 0; j < 4; j++) {
            sb0[j]     = (short)f2bf(w00[j]);
            sb0[j + 4] = (short)f2bf(w01[j]);
            sb1[j]     = (short)f2bf(w10[j]);
            sb1[j + 4] = (short)f2bf(w11[j]);
        }
        *(short8*)lB0 = sb0;
        *(short8*)lB1 = sb1;
        __syncthreads();                 // tile visible
        short8 av[4], bv[4];
#pragma unroll
        for (int mi = 0; mi < 4; mi++) av[mi] = *(const short8*)(pa + mi * 16 * 32);
#pragma unroll
        for (int ni = 0; ni < 4; ni++) bv[ni] = *(const short8*)(pb + ni * 16 * 32);
#pragma unroll
        for (int mi = 0; mi < 4; mi++)
#pragma unroll
            for (int ni = 0; ni < 4; ni++)
                acc[mi][ni] = __builtin_amdgcn_mfma_f32_16x16x32_bf16(av[mi], bv[ni], acc[mi][ni], 0, 0, 0);
    }
    // epilogue: C/D layout col=lane&15, row=(lane>>4)*4+reg
    const int cr = wm + (lane >> 4) * 4;
    const int cc = wn + (lane & 15);
#pragma unroll
    for (int mi = 0; mi < 4; mi++)
#pragma unroll
        for (int ni = 0; ni < 4; ni++)
#pragma unroll
            for (int j = 0; j < 4; j++)
                C[(size_t)(m0 + cr + mi * 16 + j) * D_ + (n0 + cc + ni * 16)] = acc[mi][ni][j];
}

__global__ __launch_bounds__(256) void gemm4_kernel(const u16* __restrict__ x5, const float* __restrict__ Wk,
                                                    const float* __restrict__ Wv, const float* __restrict__ Wr,
                                                    const float* __restrict__ Wg, float* __restrict__ kvrg)
{
    const int mm = blockIdx.z;   // 0:k(x5[0]) 1:v(x5[2]) 2:r(x5[3]) 3:g(x5[4])
    const u16* A = x5 + (size_t)(mm == 0 ? 0 : mm + 1) * M_ * D_;
    const float* W = (mm == 0) ? Wk : (mm == 1) ? Wv : (mm == 2) ? Wr : Wg;
    float* C = kvrg + (size_t)mm * M_ * D_;
    gemm_body(A, W, C);
}

__global__ __launch_bounds__(256) void gemm1_kernel(const u16* __restrict__ y, const float* __restrict__ Wo,
                                                    float* __restrict__ out)
{
    gemm_body(y, Wo, out);
}

// ---------------- sequential recurrence over T, chunked LDS staging ----------------
// one block per (b,h); wave wv stages array wv (r,k,w,v); lane: jb=lane>>3, dsub=lane&7
// chunk of CH=16 timesteps staged in LDS (double-buffered); inner loop barrier-free.
#define CH_ 16
__global__ __launch_bounds__(256) void rec_kernel(const float* __restrict__ rB, const float* __restrict__ kB,
                                                  const float* __restrict__ wB, const float* __restrict__ vB,
                                                  const float* __restrict__ fa, const float* __restrict__ state,
                                                  const int* __restrict__ ip, float* __restrict__ rwkv)
{
    const int bh = blockIdx.x;
    const int b = bh >> 5, h = bh & 31;
    const int tid = threadIdx.x;
    const int wv = tid >> 6, lane = tid & 63;
    const int jb = lane >> 3, dsub = lane & 7;
    const int d0 = wv * 8 + dsub;               // 0..31
    const int jbase = jb * 8;

    __shared__ float stage[2][4][CH_][64];      // [buf][array r,k,w,v][ts][ch]

    float S0v[8], S1v[8], faj[8];
    {
        const float* Sp = state + (size_t)b * ST_ * D_ + (size_t)(66 * ip[0] + 2) * D_ + (size_t)h * HS_ * HS_;
#pragma unroll
        for (int jj = 0; jj < 8; jj++) {
            S0v[jj] = Sp[(jbase + jj) * 64 + d0];
            S1v[jj] = Sp[(jbase + jj) * 64 + d0 + 32];
            faj[jj] = fa[h * 64 + jbase + jj];
        }
    }
    const size_t base = ((size_t)b * T_ * H_ + h) * HS_;
    const float* mysrc = (wv == 0) ? rB : (wv == 1) ? kB : (wv == 2) ? wB : vB;
    // staging address pattern: lane covers (ts = p*4 + (lane>>4), ch4 = (lane&15)*4)
    const int sts = lane >> 4;                  // 0..3
    const int sch = (lane & 15) * 4;            // 0..60

    f32x4 pre[4];
#pragma unroll
    for (int p = 0; p < 4; p++)
        pre[p] = *(const f32x4*)(mysrc + base + (size_t)(p * 4 + sts) * (H_ * HS_) + sch);
#pragma unroll
    for (int p = 0; p < 4; p++)
        *(f32x4*)&stage[0][wv][p * 4 + sts][sch] = pre[p];
    __syncthreads();

    int cb = 0;
    for (int c = 0; c < T_ / CH_; ++c) {
        const bool more = (c + 1 < T_ / CH_);
        if (more) {
#pragma unroll
            for (int p = 0; p < 4; p++)
                pre[p] = *(const f32x4*)(mysrc + base + (size_t)((c + 1) * CH_ + p * 4 + sts) * (H_ * HS_) + sch);
        }
#pragma unroll 4
        for (int ts = 0; ts < CH_; ++ts) {
            f32x4 r0 = *(const f32x4*)&stage[cb][0][ts][jbase];
            f32x4 r1 = *(const f32x4*)&stage[cb][0][ts][jbase + 4];
            f32x4 k0 = *(const f32x4*)&stage[cb][1][ts][jbase];
            f32x4 k1 = *(const f32x4*)&stage[cb][1][ts][jbase + 4];
            f32x4 w0 = *(const f32x4*)&stage[cb][2][ts][jbase];
            f32x4 w1 = *(const f32x4*)&stage[cb][2][ts][jbase + 4];
            const float vd0 = stage[cb][3][ts][d0];
            const float vd1 = stage[cb][3][ts][d0 + 32];

            float s1 = 0.f, s2a = 0.f, s2b = 0.f;
#pragma unroll
            for (int q = 0; q < 4; q++) {
                s1  = fmaf(r0[q] * faj[q], k0[q], s1);
                s2a = fmaf(r0[q], S0v[q], s2a);
                s2b = fmaf(r0[q], S1v[q], s2b);
                s1  = fmaf(r1[q] * faj[q + 4], k1[q], s1);
                s2a = fmaf(r1[q], S0v[q + 4], s2a);
                s2b = fmaf(r1[q], S1v[q + 4], s2b);
            }
#pragma unroll
            for (int off = 8; off <= 32; off <<= 1) {
                s1  += __shfl_xor(s1, off, 64);
                s2a += __shfl_xor(s2a, off, 64);
                s2b += __shfl_xor(s2b, off, 64);
            }
            if (jb == 0) {
                float* o = rwkv + base + (size_t)(c * CH_ + ts) * (H_ * HS_);
                o[d0]      = fmaf(vd0, s1, s2a);
                o[d0 + 32] = fmaf(vd1, s1, s2b);
            }
#pragma unroll
            for (int q = 0; q < 4; q++) {
                S0v[q]     = fmaf(w0[q], S0v[q],     k0[q] * vd0);
                S1v[q]     = fmaf(w0[q], S1v[q],     k0[q] * vd1);
                S0v[q + 4] = fmaf(w1[q], S0v[q + 4], k1[q] * vd0);
                S1v[q + 4] = fmaf(w1[q], S1v[q + 4], k1[q] * vd1);
            }
        }
        if (more) {
#pragma unroll
            for (int p = 0; p < 4; p++)
                *(f32x4*)&stage[cb ^ 1][wv][p * 4 + sts][sch] = pre[p];
        }
        __syncthreads();
        cb ^= 1;
    }
}

// ---------------- groupnorm + gate: y = (gn(rwkv)*lnxw+lnxb) * silu(gpre), bf16 ----------------
__global__ __launch_bounds__(256) void gn_kernel(const float* __restrict__ rwkv, const float* __restrict__ gpre,
                                                 const float* __restrict__ lnxw, const float* __restrict__ lnxb,
                                                 u16* __restrict__ y)
{
    const int g = blockIdx.x * 4 + (threadIdx.x >> 6);   // (b*T+t)*H + h
    const int lane = threadIdx.x & 63;
    const size_t e = (size_t)g * 64 + lane;
    const float val = rwkv[e];
    float s = val, q = val * val;
#pragma unroll
    for (int off = 1; off < 64; off <<= 1) { s += __shfl_xor(s, off, 64); q += __shfl_xor(q, off, 64); }
    const float mu = s * (1.f / 64.f);
    const float var = q * (1.f / 64.f) - mu * mu;
    const float rs = rsqrtf(var + EPS_);
    const int hj = (int)(e & (size_t)(D_ - 1));
    const float nrm = (val - mu) * rs * lnxw[hj] + lnxb[hj];
    const float gp = gpre[e];
    const float gv = gp / (1.f + expf(-gp));
    y[e] = f2bf(nrm * gv);
}

extern "C" void kernel_launch(void* const* d_in, const int* in_sizes, int n_in,
                              void* d_out, int out_size, void* d_ws, size_t ws_size,
                              hipStream_t stream)
{
    const float* x     = (const float*)d_in[0];
    const float* state = (const float*)d_in[1];
    const float* ln1w  = (const float*)d_in[2];
    const float* ln1b  = (const float*)d_in[3];
    const float* maax  = (const float*)d_in[4];
    const float* w1    = (const float*)d_in[5];
    const float* w2    = (const float*)d_in[6];
    const float* maak  = (const float*)d_in[7];
    const float* maaw  = (const float*)d_in[8];
    const float* maav  = (const float*)d_in[9];
    const float* maar  = (const float*)d_in[10];
    const float* maag  = (const float*)d_in[11];
    const float* tdec  = (const float*)d_in[12];
    const float* dw1   = (const float*)d_in[13];
    const float* dw2   = (const float*)d_in[14];
    const float* fa    = (const float*)d_in[15];
    const float* wrec  = (const float*)d_in[16];
    const float* wkey  = (const float*)d_in[17];
    const float* wval  = (const float*)d_in[18];
    const float* wout  = (const float*)d_in[19];
    const float* wgate = (const float*)d_in[20];
    const float* lnxw  = (const float*)d_in[21];
    const float* lnxb  = (const float*)d_in[22];
    const int*   ip    = (const int*)d_in[23];

    char* ws = (char*)d_ws;
    const size_t MD = (size_t)M_ * D_;
    float* xln  = (float*)(ws);
    float* sx   = (float*)(ws + ((size_t)4  << 20));
    float* xxx  = (float*)(ws + ((size_t)8  << 20));
    float* t5   = (float*)(ws + ((size_t)12 << 20));
    u16*   x5   = (u16*)  (ws + ((size_t)13 << 20));
    float* td   = (float*)(ws + ((size_t)23 << 20));
    float* wdec = (float*)(ws + ((size_t)24 << 20));
    float* kvrg = (float*)(ws + ((size_t)28 << 20));
    float* rwkv = (float*)(ws + ((size_t)44 << 20));
    u16*   y    = (u16*)  (ws + ((size_t)48 << 20));
    float* out  = (float*)d_out;

    hipLaunchKernelGGL(ln_kernel,     dim3(512),      dim3(256), 0, stream, x, ln1w, ln1b, xln);
    hipLaunchKernelGGL(shift_kernel,  dim3(1024),     dim3(256), 0, stream, xln, state, maax, ip, sx, xxx);
    hipLaunchKernelGGL(maa1_kernel,   dim3(320),      dim3(256), 0, stream, xxx, w1, t5);
    hipLaunchKernelGGL(maa2_kernel,   dim3(5120),     dim3(256), 0, stream, t5, w2, xln, sx, maak, maaw, maav, maar, maag, x5);
    hipLaunchKernelGGL(decay1_kernel, dim3(128),      dim3(256), 0, stream, x5, dw1, td);
    hipLaunchKernelGGL(decay2_kernel, dim3(1024),     dim3(256), 0, stream, td, dw2, tdec, wdec);
    hipLaunchKernelGGL(gemm4_kernel,  dim3(16, 4, 4), dim3(256), 0, stream, x5, wkey, wval, wrec, wgate, kvrg);
    hipLaunchKernelGGL(rec_kernel,    dim3(64),       dim3(256), 0, stream, kvrg + 2 * MD, kvrg, wdec, kvrg + MD, fa, state, ip, rwkv);
    hipLaunchKernelGGL(gn_kernel,     dim3(4096),     dim3(256), 0, stream, rwkv, kvrg + 3 * MD, lnxw, lnxb, y);
    hipLaunchKernelGGL(gemm1_kernel,  dim3(16, 4, 1), dim3(256), 0, stream, y, wout, out);

    (void)in_sizes; (void)n_in; (void)out_size; (void)ws_size;
}

// Round 3
// 310.210 us; speedup vs baseline: 1.3990x; 1.1830x over previous
//
#include <hip/hip_runtime.h>
#include <hip/hip_bf16.h>

typedef unsigned short u16;
typedef __attribute__((ext_vector_type(4))) float f32x4;
typedef __attribute__((ext_vector_type(8))) short short8;  // 8 bf16 raw bits

#define B_ 2
#define T_ 256
#define D_ 2048
#define H_ 32
#define HS_ 64
#define M_ 512          // B*T
#define ST_ 66
#define EPS_ 1e-5f

__device__ __forceinline__ float bf2f(u16 u) {
    union { unsigned int i; float f; } c; c.i = ((unsigned int)u) << 16; return c.f;
}
__device__ __forceinline__ u16 f2bf(float f) {
    union { unsigned int i; float f; } c; c.f = f;
    unsigned int r = c.i + 0x7fffu + ((c.i >> 16) & 1u);   // round-to-nearest-even
    return (u16)(r >> 16);
}
__device__ __forceinline__ u16 f2bf_hw(float f) {
    __hip_bfloat16 b = __float2bfloat16(f);
    return *reinterpret_cast<u16*>(&b);
}

// ---------------- LayerNorm: x -> xln ----------------
__global__ __launch_bounds__(256) void ln_kernel(const float* __restrict__ x, const float* __restrict__ w,
                                                 const float* __restrict__ bias, float* __restrict__ xln)
{
    const int row = blockIdx.x;                 // 0..511
    const float* xr = x + (size_t)row * D_;
    float* orow = xln + (size_t)row * D_;
    const int t = threadIdx.x;
    f32x4 a0 = *(const f32x4*)(xr + t * 8);
    f32x4 a1 = *(const f32x4*)(xr + t * 8 + 4);
    float s = 0.f, q = 0.f;
#pragma unroll
    for (int i = 0; i < 4; i++) { s += a0[i] + a1[i]; q += a0[i]*a0[i] + a1[i]*a1[i]; }
#pragma unroll
    for (int off = 1; off < 64; off <<= 1) { s += __shfl_xor(s, off, 64); q += __shfl_xor(q, off, 64); }
    __shared__ float ls[4], lq[4];
    const int wid = t >> 6, lane = t & 63;
    if (lane == 0) { ls[wid] = s; lq[wid] = q; }
    __syncthreads();
    s = ls[0] + ls[1] + ls[2] + ls[3];
    q = lq[0] + lq[1] + lq[2] + lq[3];
    const float mu = s * (1.f / D_);
    const float var = q * (1.f / D_) - mu * mu;
    const float rs = rsqrtf(var + EPS_);
#pragma unroll
    for (int i = 0; i < 8; i++) {
        int d = t * 8 + i;
        float f = (i < 4) ? a0[i] : a1[i - 4];
        orow[d] = (f - mu) * rs * w[d] + bias[d];
    }
}

// ---------------- token shift: sx = prev - cur ; xxx = xln + sx*maa_x ----------------
__global__ __launch_bounds__(256) void shift_kernel(const float* __restrict__ xln, const float* __restrict__ state,
                                                    const float* __restrict__ maax, const int* __restrict__ ip,
                                                    float* __restrict__ sx, float* __restrict__ xxx)
{
    const size_t gid = (size_t)blockIdx.x * 256 + threadIdx.x;
    const size_t e = gid * 4;                   // 4 floats per thread
    const int row = (int)(e >> 11);
    const int d = (int)(e & 2047);
    const int tt = row & (T_ - 1);
    const int b = row >> 8;
    const float* prev;
    if (tt == 0) prev = state + ((size_t)b * ST_ + (size_t)(66 * ip[0] + 1)) * D_ + d;
    else         prev = xln + e - D_;
    f32x4 p = *(const f32x4*)prev;
    f32x4 c = *(const f32x4*)(xln + e);
    f32x4 mx = *(const f32x4*)(maax + d);
    f32x4 sv, xv;
#pragma unroll
    for (int i = 0; i < 4; i++) { sv[i] = p[i] - c[i]; xv[i] = c[i] + sv[i] * mx[i]; }
    *(f32x4*)(sx + e) = sv;
    *(f32x4*)(xxx + e) = xv;
}

// ---------------- maa lora stage 1: t5 = tanh(xxx @ w1)   [512][160] ----------------
__global__ __launch_bounds__(256) void maa1_kernel(const float* __restrict__ xxx, const float* __restrict__ w1,
                                                   float* __restrict__ t5)
{
    const int gid = blockIdx.x * 256 + threadIdx.x;   // < 81920
    const int m = gid / 160, n = gid - m * 160;
    const float* xr = xxx + (size_t)m * D_;
    const float* wp = w1 + n;
    float acc = 0.f;
    for (int k = 0; k < D_; k += 8) {
        f32x4 x0 = *(const f32x4*)(xr + k);
        f32x4 x1 = *(const f32x4*)(xr + k + 4);
#pragma unroll
        for (int j = 0; j < 4; j++) {
            acc = fmaf(x0[j], wp[(size_t)(k + j) * 160], acc);
            acc = fmaf(x1[j], wp[(size_t)(k + 4 + j) * 160], acc);
        }
    }
    t5[gid] = tanhf(acc);
}

// ---------------- maa lora stage 2 + x5 build (bf16) ----------------
__global__ __launch_bounds__(256) void maa2_kernel(const float* __restrict__ t5, const float* __restrict__ w2,
                                                   const float* __restrict__ xln, const float* __restrict__ sxp,
                                                   const float* __restrict__ mk, const float* __restrict__ mw,
                                                   const float* __restrict__ mv, const float* __restrict__ mr,
                                                   const float* __restrict__ mg, u16* __restrict__ x5)
{
    const int gid = blockIdx.x * 256 + threadIdx.x;   // 5*2048*128
    const int d = gid & (D_ - 1);
    const int f = (gid >> 11) % 5;
    const int mg4 = gid / (5 * D_);                   // 0..127
    const float* maa = (f == 0) ? mk : (f == 1) ? mw : (f == 2) ? mv : (f == 3) ? mr : mg;
    const float mf = maa[d];
    const float* w2f = w2 + (size_t)f * 32 * D_ + d;
    const float* t5b = t5 + (size_t)mg4 * 4 * 160 + f * 32;
    float a0 = 0, a1 = 0, a2 = 0, a3 = 0;
#pragma unroll 8
    for (int r = 0; r < 32; r++) {
        float wv = w2f[(size_t)r * D_];
        a0 = fmaf(t5b[r], wv, a0);
        a1 = fmaf(t5b[160 + r], wv, a1);
        a2 = fmaf(t5b[320 + r], wv, a2);
        a3 = fmaf(t5b[480 + r], wv, a3);
    }
    const float accs[4] = {a0, a1, a2, a3};
    const size_t m0 = (size_t)mg4 * 4;
#pragma unroll
    for (int mm = 0; mm < 4; mm++) {
        size_t e = (m0 + mm) * D_ + d;
        x5[(size_t)f * M_ * D_ + e] = f2bf(xln[e] + sxp[e] * (mf + accs[mm]));
    }
}

// ---------------- decay lora stage 1: td = tanh(x5[1] @ dw1)  [512][64] ----------------
__global__ __launch_bounds__(256) void decay1_kernel(const u16* __restrict__ x5, const float* __restrict__ dw1,
                                                     float* __restrict__ td)
{
    const int gid = blockIdx.x * 256 + threadIdx.x;   // 32768
    const int n = gid & 63, m = gid >> 6;
    const u16* xr = x5 + (size_t)(M_ + m) * D_;       // f = 1 slice
    const float* wp = dw1 + n;
    float acc = 0.f;
    for (int k = 0; k < D_; k += 8) {
        short8 xv = *(const short8*)(xr + k);
#pragma unroll
        for (int j = 0; j < 8; j++) acc = fmaf(bf2f((u16)xv[j]), wp[(size_t)(k + j) * 64], acc);
    }
    td[gid] = tanhf(acc);
}

// ---------------- decay lora stage 2: w = exp(-exp(time_decay + td @ dw2)) ----------------
__global__ __launch_bounds__(256) void decay2_kernel(const float* __restrict__ td, const float* __restrict__ dw2,
                                                     const float* __restrict__ tdec, float* __restrict__ wout)
{
    const int gid = blockIdx.x * 256 + threadIdx.x;   // 2048*128
    const int d = gid & (D_ - 1);
    const int mg4 = gid >> 11;                        // 0..127
    const float* wp = dw2 + d;
    const float* tb = td + (size_t)mg4 * 4 * 64;
    float a0 = 0, a1 = 0, a2 = 0, a3 = 0;
#pragma unroll 8
    for (int r = 0; r < 64; r++) {
        float wv = wp[(size_t)r * D_];
        a0 = fmaf(tb[r], wv, a0);
        a1 = fmaf(tb[64 + r], wv, a1);
        a2 = fmaf(tb[128 + r], wv, a2);
        a3 = fmaf(tb[192 + r], wv, a3);
    }
    const float base = tdec[d];
    const float accs[4] = {a0, a1, a2, a3};
#pragma unroll
    for (int mm = 0; mm < 4; mm++)
        wout[((size_t)mg4 * 4 + mm) * D_ + d] = expf(-expf(base + accs[mm]));
}

// ---------------- bf16 MFMA GEMM with register double-buffer ----------------
__device__ __forceinline__ void gemm_body(const u16* __restrict__ A, const float* __restrict__ W,
                                          float* __restrict__ C)
{
    __shared__ u16 As[128 * 32];
    __shared__ u16 Bs[128 * 32];
    const int tid = threadIdx.x;
    const int m0 = blockIdx.y * 128;
    const int n0 = blockIdx.x * 128;
    const int lane = tid & 63;
    const int wid = tid >> 6;
    const int wm = (wid >> 1) * 64;
    const int wn = (wid & 1) * 64;

    f32x4 acc[4][4];
#pragma unroll
    for (int i = 0; i < 4; i++)
#pragma unroll
        for (int j = 0; j < 4; j++) { acc[i][j][0] = 0.f; acc[i][j][1] = 0.f; acc[i][j][2] = 0.f; acc[i][j][3] = 0.f; }

    const int rA = tid >> 2;            // 0..63
    const int kA = (tid & 3) * 8;       // 0,8,16,24
    const u16* gA0 = A + (size_t)(m0 + rA) * D_ + kA;
    const u16* gA1 = A + (size_t)(m0 + rA + 64) * D_ + kA;
    const float* gW0 = W + (size_t)(n0 + rA) * D_ + kA;
    const float* gW1 = W + (size_t)(n0 + rA + 64) * D_ + kA;
    u16* lA0 = As + tid * 8;
    u16* lA1 = As + (tid + 256) * 8;
    u16* lB0 = Bs + tid * 8;
    u16* lB1 = Bs + (tid + 256) * 8;

    const u16* pa = As + (size_t)(wm + (lane & 15)) * 32 + (lane >> 4) * 8;
    const u16* pb = Bs + (size_t)(wn + (lane & 15)) * 32 + (lane >> 4) * 8;

    // register double-buffer: tile kt resident in regs while kt+32 is in flight
    short8 a0 = *(const short8*)(gA0);
    short8 a1 = *(const short8*)(gA1);
    f32x4 w00 = *(const f32x4*)(gW0);
    f32x4 w01 = *(const f32x4*)(gW0 + 4);
    f32x4 w10 = *(const f32x4*)(gW1);
    f32x4 w11 = *(const f32x4*)(gW1 + 4);

    for (int kt = 0; kt < D_; kt += 32) {
        const int kt2 = (kt + 32) & (D_ - 1);     // wraps to 0 on last iter (harmless)
        short8 na0 = *(const short8*)(gA0 + kt2);
        short8 na1 = *(const short8*)(gA1 + kt2);
        f32x4 nw00 = *(const f32x4*)(gW0 + kt2);
        f32x4 nw01 = *(const f32x4*)(gW0 + kt2 + 4);
        f32x4 nw10 = *(const f32x4*)(gW1 + kt2);
        f32x4 nw11 = *(const f32x4*)(gW1 + kt2 + 4);
        __syncthreads();                 // everyone done reading previous tile
        *(short8*)lA0 = a0;
        *(short8*)lA1 = a1;
        short8 sb0, sb1;
#pragma unroll
        for (int j = 0; j < 4; j++) {
            sb0[j]     = (short)f2bf_hw(w00[j]);
            sb0[j + 4] = (short)f2bf_hw(w01[j]);
            sb1[j]     = (short)f2bf_hw(w10[j]);
            sb1[j + 4] = (short)f2bf_hw(w11[j]);
        }
        *(short8*)lB0 = sb0;
        *(short8*)lB1 = sb1;
        __syncthreads();                 // tile visible
        short8 av[4], bv[4];
#pragma unroll
        for (int mi = 0; mi < 4; mi++) av[mi] = *(const short8*)(pa + mi * 16 * 32);
#pragma unroll
        for (int ni = 0; ni < 4; ni++) bv[ni] = *(const short8*)(pb + ni * 16 * 32);
#pragma unroll
        for (int mi = 0; mi < 4; mi++)
#pragma unroll
            for (int ni = 0; ni < 4; ni++)
                acc[mi][ni] = __builtin_amdgcn_mfma_f32_16x16x32_bf16(av[mi], bv[ni], acc[mi][ni], 0, 0, 0);
        a0 = na0; a1 = na1;
        w00 = nw00; w01 = nw01; w10 = nw10; w11 = nw11;
    }
    // epilogue: C/D layout col=lane&15, row=(lane>>4)*4+reg
    const int cr = wm + (lane >> 4) * 4;
    const int cc = wn + (lane & 15);
#pragma unroll
    for (int mi = 0; mi < 4; mi++)
#pragma unroll
        for (int ni = 0; ni < 4; ni++)
#pragma unroll
            for (int j = 0; j < 4; j++)
                C[(size_t)(m0 + cr + mi * 16 + j) * D_ + (n0 + cc + ni * 16)] = acc[mi][ni][j];
}

__global__ __launch_bounds__(256) void gemm4_kernel(const u16* __restrict__ x5, const float* __restrict__ Wk,
                                                    const float* __restrict__ Wv, const float* __restrict__ Wr,
                                                    const float* __restrict__ Wg, float* __restrict__ kvrg)
{
    const int mm = blockIdx.z;   // 0:k(x5[0]) 1:v(x5[2]) 2:r(x5[3]) 3:g(x5[4])
    const u16* A = x5 + (size_t)(mm == 0 ? 0 : mm + 1) * M_ * D_;
    const float* W = (mm == 0) ? Wk : (mm == 1) ? Wv : (mm == 2) ? Wr : Wg;
    float* C = kvrg + (size_t)mm * M_ * D_;
    gemm_body(A, W, C);
}

__global__ __launch_bounds__(256) void gemm1_kernel(const u16* __restrict__ y, const float* __restrict__ Wo,
                                                    float* __restrict__ out)
{
    gemm_body(y, Wo, out);
}

// ---------------- sequential recurrence over T, chunked staging + deferred reduction ----------------
// one block per (b,h); wave wv stages array wv (r,k,w,v); lane: jb=lane>>3, dsub=lane&7
// per-step: per-lane partials written to LDS (no shuffles); batched reduce per chunk.
#define CH_ 8
__global__ __launch_bounds__(256) void rec_kernel(const float* __restrict__ rB, const float* __restrict__ kB,
                                                  const float* __restrict__ wB, const float* __restrict__ vB,
                                                  const float* __restrict__ fa, const float* __restrict__ state,
                                                  const int* __restrict__ ip, float* __restrict__ rwkv)
{
    const int bh = blockIdx.x;
    const int b = bh >> 5, h = bh & 31;
    const int tid = threadIdx.x;
    const int wv = tid >> 6, lane = tid & 63;
    const int jb = lane >> 3, dsub = lane & 7;
    const int d0 = wv * 8 + dsub;               // 0..31
    const int jbase = jb * 8;

    __shared__ float stage[2][4][CH_][64];      // [buf][r,k,w,v][ts][d]        16 KB
    __shared__ float p2[CH_][8][64];            // [ts][jb][d ^ (jb<<3)]        16 KB
    __shared__ float p1[CH_][8];                // [ts][jb]

    float S0v[8], S1v[8], faj[8];
    {
        const float* Sp = state + (size_t)b * ST_ * D_ + (size_t)(66 * ip[0] + 2) * D_ + (size_t)h * HS_ * HS_;
#pragma unroll
        for (int jj = 0; jj < 8; jj++) {
            S0v[jj] = Sp[(jbase + jj) * 64 + d0];
            S1v[jj] = Sp[(jbase + jj) * 64 + d0 + 32];
            faj[jj] = fa[h * 64 + jbase + jj];
        }
    }
    const size_t base = ((size_t)b * T_ * H_ + h) * HS_;
    const float* mysrc = (wv == 0) ? rB : (wv == 1) ? kB : (wv == 2) ? wB : vB;
    const int sts = lane >> 4;                  // 0..3
    const int sch = (lane & 15) * 4;            // 0..60
    const bool p1w = (wv == 0 && dsub == 0);

    f32x4 pre[2];
#pragma unroll
    for (int p = 0; p < 2; p++)
        pre[p] = *(const f32x4*)(mysrc + base + (size_t)(p * 4 + sts) * (H_ * HS_) + sch);
#pragma unroll
    for (int p = 0; p < 2; p++)
        *(f32x4*)&stage[0][wv][p * 4 + sts][sch] = pre[p];
    __syncthreads();

    int cb = 0;
    for (int c = 0; c < T_ / CH_; ++c) {
        const bool more = (c + 1 < T_ / CH_);
        if (more) {
#pragma unroll
            for (int p = 0; p < 2; p++)
                pre[p] = *(const f32x4*)(mysrc + base + (size_t)((c + 1) * CH_ + p * 4 + sts) * (H_ * HS_) + sch);
        }
#pragma unroll
        for (int ts = 0; ts < CH_; ++ts) {
            f32x4 r0 = *(const f32x4*)&stage[cb][0][ts][jbase];
            f32x4 r1 = *(const f32x4*)&stage[cb][0][ts][jbase + 4];
            f32x4 k0 = *(const f32x4*)&stage[cb][1][ts][jbase];
            f32x4 k1 = *(const f32x4*)&stage[cb][1][ts][jbase + 4];
            f32x4 w0 = *(const f32x4*)&stage[cb][2][ts][jbase];
            f32x4 w1 = *(const f32x4*)&stage[cb][2][ts][jbase + 4];
            const float vd0 = stage[cb][3][ts][d0];
            const float vd1 = stage[cb][3][ts][d0 + 32];

            float s1 = 0.f, s2a = 0.f, s2b = 0.f;
#pragma unroll
            for (int q = 0; q < 4; q++) {
                s1  = fmaf(r0[q] * faj[q], k0[q], s1);
                s2a = fmaf(r0[q], S0v[q], s2a);
                s2b = fmaf(r0[q], S1v[q], s2b);
                s1  = fmaf(r1[q] * faj[q + 4], k1[q], s1);
                s2a = fmaf(r1[q], S0v[q + 4], s2a);
                s2b = fmaf(r1[q], S1v[q + 4], s2b);
            }
            p2[ts][jb][d0 ^ (jb << 3)] = s2a;
            p2[ts][jb][(d0 + 32) ^ (jb << 3)] = s2b;
            if (p1w) p1[ts][jb] = s1;
#pragma unroll
            for (int q = 0; q < 4; q++) {
                S0v[q]     = fmaf(w0[q], S0v[q],     k0[q] * vd0);
                S1v[q]     = fmaf(w0[q], S1v[q],     k0[q] * vd1);
                S0v[q + 4] = fmaf(w1[q], S0v[q + 4], k1[q] * vd0);
                S1v[q + 4] = fmaf(w1[q], S1v[q + 4], k1[q] * vd1);
            }
        }
        if (more) {
#pragma unroll
            for (int p = 0; p < 2; p++)
                *(f32x4*)&stage[cb ^ 1][wv][p * 4 + sts][sch] = pre[p];
        }
        __syncthreads();   // p2/p1 complete, next-chunk stage written
        // reduce: wave wv handles ts = wv*2 + p; lane l owns column d = l
#pragma unroll
        for (int p = 0; p < 2; p++) {
            const int ts = wv * 2 + p;
            f32x4 p1a = *(const f32x4*)&p1[ts][0];
            f32x4 p1b = *(const f32x4*)&p1[ts][4];
            float s1t = ((p1a[0] + p1a[1]) + (p1a[2] + p1a[3])) +
                        ((p1b[0] + p1b[1]) + (p1b[2] + p1b[3]));
            float s2t = 0.f;
#pragma unroll
            for (int j = 0; j < 8; j++) s2t += p2[ts][j][lane ^ (j << 3)];
            const float vvv = stage[cb][3][ts][lane];
            rwkv[base + (size_t)(c * CH_ + ts) * (H_ * HS_) + lane] = fmaf(vvv, s1t, s2t);
        }
        __syncthreads();   // protect p2/p1 before next chunk overwrites
        cb ^= 1;
    }
}

// ---------------- groupnorm + gate: y = (gn(rwkv)*lnxw+lnxb) * silu(gpre), bf16 ----------------
__global__ __launch_bounds__(256) void gn_kernel(const float* __restrict__ rwkv, const float* __restrict__ gpre,
                                                 const float* __restrict__ lnxw, const float* __restrict__ lnxb,
                                                 u16* __restrict__ y)
{
    const int g = blockIdx.x * 4 + (threadIdx.x >> 6);   // (b*T+t)*H + h
    const int lane = threadIdx.x & 63;
    const size_t e = (size_t)g * 64 + lane;
    const float val = rwkv[e];
    float s = val, q = val * val;
#pragma unroll
    for (int off = 1; off < 64; off <<= 1) { s += __shfl_xor(s, off, 64); q += __shfl_xor(q, off, 64); }
    const float mu = s * (1.f / 64.f);
    const float var = q * (1.f / 64.f) - mu * mu;
    const float rs = rsqrtf(var + EPS_);
    const int hj = (int)(e & (size_t)(D_ - 1));
    const float nrm = (val - mu) * rs * lnxw[hj] + lnxb[hj];
    const float gp = gpre[e];
    const float gv = gp / (1.f + expf(-gp));
    y[e] = f2bf(nrm * gv);
}

extern "C" void kernel_launch(void* const* d_in, const int* in_sizes, int n_in,
                              void* d_out, int out_size, void* d_ws, size_t ws_size,
                              hipStream_t stream)
{
    const float* x     = (const float*)d_in[0];
    const float* state = (const float*)d_in[1];
    const float* ln1w  = (const float*)d_in[2];
    const float* ln1b  = (const float*)d_in[3];
    const float* maax  = (const float*)d_in[4];
    const float* w1    = (const float*)d_in[5];
    const float* w2    = (const float*)d_in[6];
    const float* maak  = (const float*)d_in[7];
    const float* maaw  = (const float*)d_in[8];
    const float* maav  = (const float*)d_in[9];
    const float* maar  = (const float*)d_in[10];
    const float* maag  = (const float*)d_in[11];
    const float* tdec  = (const float*)d_in[12];
    const float* dw1   = (const float*)d_in[13];
    const float* dw2   = (const float*)d_in[14];
    const float* fa    = (const float*)d_in[15];
    const float* wrec  = (const float*)d_in[16];
    const float* wkey  = (const float*)d_in[17];
    const float* wval  = (const float*)d_in[18];
    const float* wout  = (const float*)d_in[19];
    const float* wgate = (const float*)d_in[20];
    const float* lnxw  = (const float*)d_in[21];
    const float* lnxb  = (const float*)d_in[22];
    const int*   ip    = (const int*)d_in[23];

    char* ws = (char*)d_ws;
    const size_t MD = (size_t)M_ * D_;
    float* xln  = (float*)(ws);
    float* sx   = (float*)(ws + ((size_t)4  << 20));
    float* xxx  = (float*)(ws + ((size_t)8  << 20));
    float* t5   = (float*)(ws + ((size_t)12 << 20));
    u16*   x5   = (u16*)  (ws + ((size_t)13 << 20));
    float* td   = (float*)(ws + ((size_t)23 << 20));
    float* wdec = (float*)(ws + ((size_t)24 << 20));
    float* kvrg = (float*)(ws + ((size_t)28 << 20));
    float* rwkv = (float*)(ws + ((size_t)44 << 20));
    u16*   y    = (u16*)  (ws + ((size_t)48 << 20));
    float* out  = (float*)d_out;

    hipLaunchKernelGGL(ln_kernel,     dim3(512),      dim3(256), 0, stream, x, ln1w, ln1b, xln);
    hipLaunchKernelGGL(shift_kernel,  dim3(1024),     dim3(256), 0, stream, xln, state, maax, ip, sx, xxx);
    hipLaunchKernelGGL(maa1_kernel,   dim3(320),      dim3(256), 0, stream, xxx, w1, t5);
    hipLaunchKernelGGL(maa2_kernel,   dim3(5120),     dim3(256), 0, stream, t5, w2, xln, sx, maak, maaw, maav, maar, maag, x5);
    hipLaunchKernelGGL(decay1_kernel, dim3(128),      dim3(256), 0, stream, x5, dw1, td);
    hipLaunchKernelGGL(decay2_kernel, dim3(1024),     dim3(256), 0, stream, td, dw2, tdec, wdec);
    hipLaunchKernelGGL(gemm4_kernel,  dim3(16, 4, 4), dim3(256), 0, stream, x5, wkey, wval, wrec, wgate, kvrg);
    hipLaunchKernelGGL(rec_kernel,    dim3(64),       dim3(256), 0, stream, kvrg + 2 * MD, kvrg, wdec, kvrg + MD, fa, state, ip, rwkv);
    hipLaunchKernelGGL(gn_kernel,     dim3(4096),     dim3(256), 0, stream, rwkv, kvrg + 3 * MD, lnxw, lnxb, y);
    hipLaunchKernelGGL(gemm1_kernel,  dim3(16, 4, 1), dim3(256), 0, stream, y, wout, out);

    (void)in_sizes; (void)n_in; (void)out_size; (void)ws_size;
}

// Round 5
// 250.354 us; speedup vs baseline: 1.7335x; 1.2391x over previous
//
#include <hip/hip_runtime.h>
#include <hip/hip_bf16.h>

typedef unsigned short u16;
typedef __attribute__((ext_vector_type(4))) float f32x4;
typedef __attribute__((ext_vector_type(8))) short short8;  // 8 bf16 raw bits
typedef __attribute__((ext_vector_type(4))) short bf16x4;

#define B_ 2
#define T_ 256
#define D_ 2048
#define H_ 32
#define HS_ 64
#define M_ 512          // B*T
#define ST_ 66
#define EPS_ 1e-5f

__device__ __forceinline__ float bf2f(u16 u) {
    union { unsigned int i; float f; } c; c.i = ((unsigned int)u) << 16; return c.f;
}
__device__ __forceinline__ u16 f2bf(float f) {
    union { unsigned int i; float f; } c; c.f = f;
    unsigned int r = c.i + 0x7fffu + ((c.i >> 16) & 1u);   // round-to-nearest-even
    return (u16)(r >> 16);
}
__device__ __forceinline__ u16 f2bf_hw(float f) {
    __hip_bfloat16 b = __float2bfloat16(f);
    return *reinterpret_cast<u16*>(&b);
}

// ---------------- LayerNorm: x -> xln ----------------
__global__ __launch_bounds__(256) void ln_kernel(const float* __restrict__ x, const float* __restrict__ w,
                                                 const float* __restrict__ bias, float* __restrict__ xln)
{
    const int row = blockIdx.x;                 // 0..511
    const float* xr = x + (size_t)row * D_;
    float* orow = xln + (size_t)row * D_;
    const int t = threadIdx.x;
    f32x4 a0 = *(const f32x4*)(xr + t * 8);
    f32x4 a1 = *(const f32x4*)(xr + t * 8 + 4);
    float s = 0.f, q = 0.f;
#pragma unroll
    for (int i = 0; i < 4; i++) { s += a0[i] + a1[i]; q += a0[i]*a0[i] + a1[i]*a1[i]; }
#pragma unroll
    for (int off = 1; off < 64; off <<= 1) { s += __shfl_xor(s, off, 64); q += __shfl_xor(q, off, 64); }
    __shared__ float ls[4], lq[4];
    const int wid = t >> 6, lane = t & 63;
    if (lane == 0) { ls[wid] = s; lq[wid] = q; }
    __syncthreads();
    s = ls[0] + ls[1] + ls[2] + ls[3];
    q = lq[0] + lq[1] + lq[2] + lq[3];
    const float mu = s * (1.f / D_);
    const float var = q * (1.f / D_) - mu * mu;
    const float rs = rsqrtf(var + EPS_);
#pragma unroll
    for (int i = 0; i < 8; i++) {
        int d = t * 8 + i;
        float f = (i < 4) ? a0[i] : a1[i - 4];
        orow[d] = (f - mu) * rs * w[d] + bias[d];
    }
}

// ---------------- token shift: sx = prev - cur ; xxxb = bf16(xln + sx*maa_x) ----------------
__global__ __launch_bounds__(256) void shift_kernel(const float* __restrict__ xln, const float* __restrict__ state,
                                                    const float* __restrict__ maax, const int* __restrict__ ip,
                                                    float* __restrict__ sx, u16* __restrict__ xxxb)
{
    const size_t gid = (size_t)blockIdx.x * 256 + threadIdx.x;
    const size_t e = gid * 4;                   // 4 floats per thread
    const int row = (int)(e >> 11);
    const int d = (int)(e & 2047);
    const int tt = row & (T_ - 1);
    const int b = row >> 8;
    const float* prev;
    if (tt == 0) prev = state + ((size_t)b * ST_ + (size_t)(66 * ip[0] + 1)) * D_ + d;
    else         prev = xln + e - D_;
    f32x4 p = *(const f32x4*)prev;
    f32x4 c = *(const f32x4*)(xln + e);
    f32x4 mx = *(const f32x4*)(maax + d);
    f32x4 sv;
    bf16x4 xv;
#pragma unroll
    for (int i = 0; i < 4; i++) { sv[i] = p[i] - c[i]; xv[i] = (short)f2bf(c[i] + sv[i] * mx[i]); }
    *(f32x4*)(sx + e) = sv;
    *(bf16x4*)(xxxb + e) = xv;
}

// ---------------- transpose + bf16: out[n][k] = bf16(in[k][n]) ----------------
// grid (K/32, N/32), 256 threads
__global__ __launch_bounds__(256) void txp_kernel(const float* __restrict__ in, u16* __restrict__ out,
                                                  int K, int N)
{
    __shared__ float tile[32][33];
    const int k0 = blockIdx.x * 32, n0 = blockIdx.y * 32;
    const int c = threadIdx.x & 31, r8 = threadIdx.x >> 5;   // 0..7
#pragma unroll
    for (int i = 0; i < 4; i++) {
        int r = r8 + i * 8;
        tile[r][c] = in[(size_t)(k0 + r) * N + (n0 + c)];
    }
    __syncthreads();
#pragma unroll
    for (int i = 0; i < 4; i++) {
        int r = r8 + i * 8;
        out[(size_t)(n0 + r) * K + (k0 + c)] = f2bf(tile[c][r]);
    }
}

// ---------------- small-N MFMA GEMM: C[m,n] = act(sum_k A[m,k]*Wt[n,k]) ----------------
// A bf16 [M][2048], Wt bf16 [NN][2048]; block tile 128(M) x 64(N); optional tanh epilogue.
template<int NN, bool TANH>
__global__ __launch_bounds__(256) void gsmall_kernel(const u16* __restrict__ A, const u16* __restrict__ Wt,
                                                     float* __restrict__ C, int ldc)
{
    __shared__ u16 As[128 * 32];
    __shared__ u16 Ws[64 * 32];
    const int tid = threadIdx.x;
    const int m0 = blockIdx.y * 128, n0 = blockIdx.x * 64;
    const int lane = tid & 63, wid = tid >> 6;
    const int wm = (wid >> 1) * 64, wn = (wid & 1) * 32;

    f32x4 acc[4][2];
#pragma unroll
    for (int i = 0; i < 4; i++)
#pragma unroll
        for (int j = 0; j < 2; j++) { acc[i][j][0]=0.f; acc[i][j][1]=0.f; acc[i][j][2]=0.f; acc[i][j][3]=0.f; }

    const int rA = tid >> 2;            // 0..63
    const int kA = (tid & 3) * 8;       // 0,8,16,24
    const u16* gA0 = A + (size_t)(m0 + rA) * D_ + kA;
    const u16* gA1 = A + (size_t)(m0 + rA + 64) * D_ + kA;
    int wrow = n0 + rA; if (wrow >= NN) wrow = NN - 1;
    const u16* gW = Wt + (size_t)wrow * D_ + kA;
    u16* lA0 = As + tid * 8;
    u16* lA1 = As + (tid + 256) * 8;
    u16* lW  = Ws + tid * 8;
    const u16* pa = As + (size_t)(wm + (lane & 15)) * 32 + (lane >> 4) * 8;
    const u16* pb = Ws + (size_t)(wn + (lane & 15)) * 32 + (lane >> 4) * 8;

    short8 a0 = *(const short8*)gA0;
    short8 a1 = *(const short8*)gA1;
    short8 w0 = *(const short8*)gW;

    for (int kt = 0; kt < D_; kt += 32) {
        const int kt2 = (kt + 32) & (D_ - 1);
        short8 na0 = *(const short8*)(gA0 + kt2);
        short8 na1 = *(const short8*)(gA1 + kt2);
        short8 nw0 = *(const short8*)(gW + kt2);
        __syncthreads();
        *(short8*)lA0 = a0;
        *(short8*)lA1 = a1;
        *(short8*)lW  = w0;
        __syncthreads();
        short8 av[4], bv[2];
#pragma unroll
        for (int mi = 0; mi < 4; mi++) av[mi] = *(const short8*)(pa + mi * 16 * 32);
#pragma unroll
        for (int ni = 0; ni < 2; ni++) bv[ni] = *(const short8*)(pb + ni * 16 * 32);
#pragma unroll
        for (int mi = 0; mi < 4; mi++)
#pragma unroll
            for (int ni = 0; ni < 2; ni++)
                acc[mi][ni] = __builtin_amdgcn_mfma_f32_16x16x32_bf16(av[mi], bv[ni], acc[mi][ni], 0, 0, 0);
        a0 = na0; a1 = na1; w0 = nw0;
    }
    const int cr = wm + (lane >> 4) * 4;
    const int cc = wn + (lane & 15);
#pragma unroll
    for (int mi = 0; mi < 4; mi++)
#pragma unroll
        for (int ni = 0; ni < 2; ni++) {
            const int col = n0 + cc + ni * 16;
            if (col < NN) {
#pragma unroll
                for (int j = 0; j < 4; j++) {
                    float v = acc[mi][ni][j];
                    if (TANH) v = tanhf(v);
                    C[(size_t)(m0 + cr + mi * 16 + j) * ldc + col] = v;
                }
            }
        }
}

// ---------------- maa lora stage 2 + x5 build (bf16) ----------------
__global__ __launch_bounds__(256) void maa2_kernel(const float* __restrict__ t5, const float* __restrict__ w2,
                                                   const float* __restrict__ xln, const float* __restrict__ sxp,
                                                   const float* __restrict__ mk, const float* __restrict__ mw,
                                                   const float* __restrict__ mv, const float* __restrict__ mr,
                                                   const float* __restrict__ mg, u16* __restrict__ x5)
{
    const int gid = blockIdx.x * 256 + threadIdx.x;   // 5*2048*128
    const int d = gid & (D_ - 1);
    const int f = (gid >> 11) % 5;
    const int mg4 = gid / (5 * D_);                   // 0..127
    const float* maa = (f == 0) ? mk : (f == 1) ? mw : (f == 2) ? mv : (f == 3) ? mr : mg;
    const float mf = maa[d];
    const float* w2f = w2 + (size_t)f * 32 * D_ + d;
    const float* t5b = t5 + (size_t)mg4 * 4 * 160 + f * 32;
    float a0 = 0, a1 = 0, a2 = 0, a3 = 0;
#pragma unroll 8
    for (int r = 0; r < 32; r++) {
        float wv = w2f[(size_t)r * D_];
        a0 = fmaf(t5b[r], wv, a0);
        a1 = fmaf(t5b[160 + r], wv, a1);
        a2 = fmaf(t5b[320 + r], wv, a2);
        a3 = fmaf(t5b[480 + r], wv, a3);
    }
    const float accs[4] = {a0, a1, a2, a3};
    const size_t m0 = (size_t)mg4 * 4;
#pragma unroll
    for (int mm = 0; mm < 4; mm++) {
        size_t e = (m0 + mm) * D_ + d;
        x5[(size_t)f * M_ * D_ + e] = f2bf(xln[e] + sxp[e] * (mf + accs[mm]));
    }
}

// ---------------- decay lora stage 2: w = exp(-exp(time_decay + td @ dw2)) ----------------
__global__ __launch_bounds__(256) void decay2_kernel(const float* __restrict__ td, const float* __restrict__ dw2,
                                                     const float* __restrict__ tdec, float* __restrict__ wout)
{
    const int gid = blockIdx.x * 256 + threadIdx.x;   // 2048*128
    const int d = gid & (D_ - 1);
    const int mg4 = gid >> 11;                        // 0..127
    const float* wp = dw2 + d;
    const float* tb = td + (size_t)mg4 * 4 * 64;
    float a0 = 0, a1 = 0, a2 = 0, a3 = 0;
#pragma unroll 8
    for (int r = 0; r < 64; r++) {
        float wv = wp[(size_t)r * D_];
        a0 = fmaf(tb[r], wv, a0);
        a1 = fmaf(tb[64 + r], wv, a1);
        a2 = fmaf(tb[128 + r], wv, a2);
        a3 = fmaf(tb[192 + r], wv, a3);
    }
    const float base = tdec[d];
    const float accs[4] = {a0, a1, a2, a3};
#pragma unroll
    for (int mm = 0; mm < 4; mm++)
        wout[((size_t)mg4 * 4 + mm) * D_ + d] = expf(-expf(base + accs[mm]));
}

// ---------------- bf16 MFMA GEMM with register double-buffer ----------------
__device__ __forceinline__ void gemm_body(const u16* __restrict__ A, const float* __restrict__ W,
                                          float* __restrict__ C)
{
    __shared__ u16 As[128 * 32];
    __shared__ u16 Bs[128 * 32];
    const int tid = threadIdx.x;
    const int m0 = blockIdx.y * 128;
    const int n0 = blockIdx.x * 128;
    const int lane = tid & 63;
    const int wid = tid >> 6;
    const int wm = (wid >> 1) * 64;
    const int wn = (wid & 1) * 64;

    f32x4 acc[4][4];
#pragma unroll
    for (int i = 0; i < 4; i++)
#pragma unroll
        for (int j = 0; j < 4; j++) { acc[i][j][0] = 0.f; acc[i][j][1] = 0.f; acc[i][j][2] = 0.f; acc[i][j][3] = 0.f; }

    const int rA = tid >> 2;            // 0..63
    const int kA = (tid & 3) * 8;       // 0,8,16,24
    const u16* gA0 = A + (size_t)(m0 + rA) * D_ + kA;
    const u16* gA1 = A + (size_t)(m0 + rA + 64) * D_ + kA;
    const float* gW0 = W + (size_t)(n0 + rA) * D_ + kA;
    const float* gW1 = W + (size_t)(n0 + rA + 64) * D_ + kA;
    u16* lA0 = As + tid * 8;
    u16* lA1 = As + (tid + 256) * 8;
    u16* lB0 = Bs + tid * 8;
    u16* lB1 = Bs + (tid + 256) * 8;

    const u16* pa = As + (size_t)(wm + (lane & 15)) * 32 + (lane >> 4) * 8;
    const u16* pb = Bs + (size_t)(wn + (lane & 15)) * 32 + (lane >> 4) * 8;

    // register double-buffer: tile kt resident in regs while kt+32 is in flight
    short8 a0 = *(const short8*)(gA0);
    short8 a1 = *(const short8*)(gA1);
    f32x4 w00 = *(const f32x4*)(gW0);
    f32x4 w01 = *(const f32x4*)(gW0 + 4);
    f32x4 w10 = *(const f32x4*)(gW1);
    f32x4 w11 = *(const f32x4*)(gW1 + 4);

    for (int kt = 0; kt < D_; kt += 32) {
        const int kt2 = (kt + 32) & (D_ - 1);     // wraps to 0 on last iter (harmless)
        short8 na0 = *(const short8*)(gA0 + kt2);
        short8 na1 = *(const short8*)(gA1 + kt2);
        f32x4 nw00 = *(const f32x4*)(gW0 + kt2);
        f32x4 nw01 = *(const f32x4*)(gW0 + kt2 + 4);
        f32x4 nw10 = *(const f32x4*)(gW1 + kt2);
        f32x4 nw11 = *(const f32x4*)(gW1 + kt2 + 4);
        __syncthreads();                 // everyone done reading previous tile
        *(short8*)lA0 = a0;
        *(short8*)lA1 = a1;
        short8 sb0, sb1;
#pragma unroll
        for (int j = 0; j < 4; j++) {
            sb0[j]     = (short)f2bf_hw(w00[j]);
            sb0[j + 4] = (short)f2bf_hw(w01[j]);
            sb1[j]     = (short)f2bf_hw(w10[j]);
            sb1[j + 4] = (short)f2bf_hw(w11[j]);
        }
        *(short8*)lB0 = sb0;
        *(short8*)lB1 = sb1;
        __syncthreads();                 // tile visible
        short8 av[4], bv[4];
#pragma unroll
        for (int mi = 0; mi < 4; mi++) av[mi] = *(const short8*)(pa + mi * 16 * 32);
#pragma unroll
        for (int ni = 0; ni < 4; ni++) bv[ni] = *(const short8*)(pb + ni * 16 * 32);
#pragma unroll
        for (int mi = 0; mi < 4; mi++)
#pragma unroll
            for (int ni = 0; ni < 4; ni++)
                acc[mi][ni] = __builtin_amdgcn_mfma_f32_16x16x32_bf16(av[mi], bv[ni], acc[mi][ni], 0, 0, 0);
        a0 = na0; a1 = na1;
        w00 = nw00; w01 = nw01; w10 = nw10; w11 = nw11;
    }
    // epilogue: C/D layout col=lane&15, row=(lane>>4)*4+reg
    const int cr = wm + (lane >> 4) * 4;
    const int cc = wn + (lane & 15);
#pragma unroll
    for (int mi = 0; mi < 4; mi++)
#pragma unroll
        for (int ni = 0; ni < 4; ni++)
#pragma unroll
            for (int j = 0; j < 4; j++)
                C[(size_t)(m0 + cr + mi * 16 + j) * D_ + (n0 + cc + ni * 16)] = acc[mi][ni][j];
}

__global__ __launch_bounds__(256) void gemm4_kernel(const u16* __restrict__ x5, const float* __restrict__ Wk,
                                                    const float* __restrict__ Wv, const float* __restrict__ Wr,
                                                    const float* __restrict__ Wg, float* __restrict__ kvrg)
{
    const int mm = blockIdx.z;   // 0:k(x5[0]) 1:v(x5[2]) 2:r(x5[3]) 3:g(x5[4])
    const u16* A = x5 + (size_t)(mm == 0 ? 0 : mm + 1) * M_ * D_;
    const float* W = (mm == 0) ? Wk : (mm == 1) ? Wv : (mm == 2) ? Wr : Wg;
    float* C = kvrg + (size_t)mm * M_ * D_;
    gemm_body(A, W, C);
}

__global__ __launch_bounds__(256) void gemm1_kernel(const u16* __restrict__ y, const float* __restrict__ Wo,
                                                    float* __restrict__ out)
{
    gemm_body(y, Wo, out);
}

// ---------------- sequential recurrence over T, chunked staging + deferred reduction ----------------
#define CH_ 8
__global__ __launch_bounds__(256) void rec_kernel(const float* __restrict__ rB, const float* __restrict__ kB,
                                                  const float* __restrict__ wB, const float* __restrict__ vB,
                                                  const float* __restrict__ fa, const float* __restrict__ state,
                                                  const int* __restrict__ ip, float* __restrict__ rwkv)
{
    const int bh = blockIdx.x;
    const int b = bh >> 5, h = bh & 31;
    const int tid = threadIdx.x;
    const int wv = tid >> 6, lane = tid & 63;
    const int jb = lane >> 3, dsub = lane & 7;
    const int d0 = wv * 8 + dsub;               // 0..31
    const int jbase = jb * 8;

    __shared__ float stage[2][4][CH_][64];      // [buf][r,k,w,v][ts][d]        16 KB
    __shared__ float p2[CH_][8][64];            // [ts][jb][d ^ (jb<<3)]        16 KB
    __shared__ float p1[CH_][8];                // [ts][jb]

    float S0v[8], S1v[8], faj[8];
    {
        const float* Sp = state + (size_t)b * ST_ * D_ + (size_t)(66 * ip[0] + 2) * D_ + (size_t)h * HS_ * HS_;
#pragma unroll
        for (int jj = 0; jj < 8; jj++) {
            S0v[jj] = Sp[(jbase + jj) * 64 + d0];
            S1v[jj] = Sp[(jbase + jj) * 64 + d0 + 32];
            faj[jj] = fa[h * 64 + jbase + jj];
        }
    }
    const size_t base = ((size_t)b * T_ * H_ + h) * HS_;
    const float* mysrc = (wv == 0) ? rB : (wv == 1) ? kB : (wv == 2) ? wB : vB;
    const int sts = lane >> 4;                  // 0..3
    const int sch = (lane & 15) * 4;            // 0..60
    const bool p1w = (wv == 0 && dsub == 0);

    f32x4 pre[2];
#pragma unroll
    for (int p = 0; p < 2; p++)
        pre[p] = *(const f32x4*)(mysrc + base + (size_t)(p * 4 + sts) * (H_ * HS_) + sch);
#pragma unroll
    for (int p = 0; p < 2; p++)
        *(f32x4*)&stage[0][wv][p * 4 + sts][sch] = pre[p];
    __syncthreads();

    int cb = 0;
    for (int c = 0; c < T_ / CH_; ++c) {
        const bool more = (c + 1 < T_ / CH_);
        if (more) {
#pragma unroll
            for (int p = 0; p < 2; p++)
                pre[p] = *(const f32x4*)(mysrc + base + (size_t)((c + 1) * CH_ + p * 4 + sts) * (H_ * HS_) + sch);
        }
#pragma unroll
        for (int ts = 0; ts < CH_; ++ts) {
            f32x4 r0 = *(const f32x4*)&stage[cb][0][ts][jbase];
            f32x4 r1 = *(const f32x4*)&stage[cb][0][ts][jbase + 4];
            f32x4 k0 = *(const f32x4*)&stage[cb][1][ts][jbase];
            f32x4 k1 = *(const f32x4*)&stage[cb][1][ts][jbase + 4];
            f32x4 w0 = *(const f32x4*)&stage[cb][2][ts][jbase];
            f32x4 w1 = *(const f32x4*)&stage[cb][2][ts][jbase + 4];
            const float vd0 = stage[cb][3][ts][d0];
            const float vd1 = stage[cb][3][ts][d0 + 32];

            float s1 = 0.f, s2a = 0.f, s2b = 0.f;
#pragma unroll
            for (int q = 0; q < 4; q++) {
                s1  = fmaf(r0[q] * faj[q], k0[q], s1);
                s2a = fmaf(r0[q], S0v[q], s2a);
                s2b = fmaf(r0[q], S1v[q], s2b);
                s1  = fmaf(r1[q] * faj[q + 4], k1[q], s1);
                s2a = fmaf(r1[q], S0v[q + 4], s2a);
                s2b = fmaf(r1[q], S1v[q + 4], s2b);
            }
            p2[ts][jb][d0 ^ (jb << 3)] = s2a;
            p2[ts][jb][(d0 + 32) ^ (jb << 3)] = s2b;
            if (p1w) p1[ts][jb] = s1;
#pragma unroll
            for (int q = 0; q < 4; q++) {
                S0v[q]     = fmaf(w0[q], S0v[q],     k0[q] * vd0);
                S1v[q]     = fmaf(w0[q], S1v[q],     k0[q] * vd1);
                S0v[q + 4] = fmaf(w1[q], S0v[q + 4], k1[q] * vd0);
                S1v[q + 4] = fmaf(w1[q], S1v[q + 4], k1[q] * vd1);
            }
        }
        if (more) {
#pragma unroll
            for (int p = 0; p < 2; p++)
                *(f32x4*)&stage[cb ^ 1][wv][p * 4 + sts][sch] = pre[p];
        }
        __syncthreads();   // p2/p1 complete, next-chunk stage written
#pragma unroll
        for (int p = 0; p < 2; p++) {
            const int ts = wv * 2 + p;
            f32x4 p1a = *(const f32x4*)&p1[ts][0];
            f32x4 p1b = *(const f32x4*)&p1[ts][4];
            float s1t = ((p1a[0] + p1a[1]) + (p1a[2] + p1a[3])) +
                        ((p1b[0] + p1b[1]) + (p1b[2] + p1b[3]));
            float s2t = 0.f;
#pragma unroll
            for (int j = 0; j < 8; j++) s2t += p2[ts][j][lane ^ (j << 3)];
            const float vvv = stage[cb][3][ts][lane];
            rwkv[base + (size_t)(c * CH_ + ts) * (H_ * HS_) + lane] = fmaf(vvv, s1t, s2t);
        }
        __syncthreads();   // protect p2/p1 before next chunk overwrites
        cb ^= 1;
    }
}

// ---------------- groupnorm + gate: y = (gn(rwkv)*lnxw+lnxb) * silu(gpre), bf16 ----------------
__global__ __launch_bounds__(256) void gn_kernel(const float* __restrict__ rwkv, const float* __restrict__ gpre,
                                                 const float* __restrict__ lnxw, const float* __restrict__ lnxb,
                                                 u16* __restrict__ y)
{
    const int g = blockIdx.x * 4 + (threadIdx.x >> 6);   // (b*T+t)*H + h
    const int lane = threadIdx.x & 63;
    const size_t e = (size_t)g * 64 + lane;
    const float val = rwkv[e];
    float s = val, q = val * val;
#pragma unroll
    for (int off = 1; off < 64; off <<= 1) { s += __shfl_xor(s, off, 64); q += __shfl_xor(q, off, 64); }
    const float mu = s * (1.f / 64.f);
    const float var = q * (1.f / 64.f) - mu * mu;
    const float rs = rsqrtf(var + EPS_);
    const int hj = (int)(e & (size_t)(D_ - 1));
    const float nrm = (val - mu) * rs * lnxw[hj] + lnxb[hj];
    const float gp = gpre[e];
    const float gv = gp / (1.f + expf(-gp));
    y[e] = f2bf(nrm * gv);
}

extern "C" void kernel_launch(void* const* d_in, const int* in_sizes, int n_in,
                              void* d_out, int out_size, void* d_ws, size_t ws_size,
                              hipStream_t stream)
{
    const float* x     = (const float*)d_in[0];
    const float* state = (const float*)d_in[1];
    const float* ln1w  = (const float*)d_in[2];
    const float* ln1b  = (const float*)d_in[3];
    const float* maax  = (const float*)d_in[4];
    const float* w1    = (const float*)d_in[5];
    const float* w2    = (const float*)d_in[6];
    const float* maak  = (const float*)d_in[7];
    const float* maaw  = (const float*)d_in[8];
    const float* maav  = (const float*)d_in[9];
    const float* maar  = (const float*)d_in[10];
    const float* maag  = (const float*)d_in[11];
    const float* tdec  = (const float*)d_in[12];
    const float* dw1   = (const float*)d_in[13];
    const float* dw2   = (const float*)d_in[14];
    const float* fa    = (const float*)d_in[15];
    const float* wrec  = (const float*)d_in[16];
    const float* wkey  = (const float*)d_in[17];
    const float* wval  = (const float*)d_in[18];
    const float* wout  = (const float*)d_in[19];
    const float* wgate = (const float*)d_in[20];
    const float* lnxw  = (const float*)d_in[21];
    const float* lnxb  = (const float*)d_in[22];
    const int*   ip    = (const int*)d_in[23];

    char* ws = (char*)d_ws;
    const size_t MD = (size_t)M_ * D_;
    float* xln  = (float*)(ws);                          // 4 MB
    float* sx   = (float*)(ws + ((size_t)4  << 20));     // 4 MB
    u16*   xxxb = (u16*)  (ws + ((size_t)8  << 20));     // 2 MB
    u16*   w1t  = (u16*)  (ws + ((size_t)10 << 20));     // 640 KB
    u16*   dw1t = (u16*)  (ws + ((size_t)11 << 20));     // 256 KB
    float* t5   = (float*)(ws + ((size_t)12 << 20));     // 320 KB
    u16*   x5   = (u16*)  (ws + ((size_t)13 << 20));     // 10 MB
    float* td   = (float*)(ws + ((size_t)23 << 20));     // 128 KB
    float* wdec = (float*)(ws + ((size_t)24 << 20));     // 4 MB
    float* kvrg = (float*)(ws + ((size_t)28 << 20));     // 16 MB
    float* rwkv = (float*)(ws + ((size_t)44 << 20));     // 4 MB
    u16*   y    = (u16*)  (ws + ((size_t)48 << 20));     // 2 MB
    float* out  = (float*)d_out;

    hipLaunchKernelGGL(ln_kernel,     dim3(512),      dim3(256), 0, stream, x, ln1w, ln1b, xln);
    hipLaunchKernelGGL(shift_kernel,  dim3(1024),     dim3(256), 0, stream, xln, state, maax, ip, sx, xxxb);
    hipLaunchKernelGGL(txp_kernel,    dim3(64, 5),    dim3(256), 0, stream, w1, w1t, D_, 160);
    hipLaunchKernelGGL(txp_kernel,    dim3(64, 2),    dim3(256), 0, stream, dw1, dw1t, D_, 64);
    hipLaunchKernelGGL((gsmall_kernel<160, true>), dim3(3, 4), dim3(256), 0, stream, xxxb, w1t, t5, 160);
    hipLaunchKernelGGL(maa2_kernel,   dim3(5120),     dim3(256), 0, stream, t5, w2, xln, sx, maak, maaw, maav, maar, maag, x5);
    hipLaunchKernelGGL((gsmall_kernel<64, true>),  dim3(1, 4), dim3(256), 0, stream, x5 + MD, dw1t, td, 64);
    hipLaunchKernelGGL(decay2_kernel, dim3(1024),     dim3(256), 0, stream, td, dw2, tdec, wdec);
    hipLaunchKernelGGL(gemm4_kernel,  dim3(16, 4, 4), dim3(256), 0, stream, x5, wkey, wval, wrec, wgate, kvrg);
    hipLaunchKernelGGL(rec_kernel,    dim3(64),       dim3(256), 0, stream, kvrg + 2 * MD, kvrg, wdec, kvrg + MD, fa, state, ip, rwkv);
    hipLaunchKernelGGL(gn_kernel,     dim3(4096),     dim3(256), 0, stream, rwkv, kvrg + 3 * MD, lnxw, lnxb, y);
    hipLaunchKernelGGL(gemm1_kernel,  dim3(16, 4, 1), dim3(256), 0, stream, y, wout, out);

    (void)in_sizes; (void)n_in; (void)out_size; (void)ws_size;
}

// Round 6
// 214.786 us; speedup vs baseline: 2.0205x; 1.1656x over previous
//
#include <hip/hip_runtime.h>
#include <hip/hip_bf16.h>

typedef unsigned short u16;
typedef __attribute__((ext_vector_type(4))) float f32x4;
typedef __attribute__((ext_vector_type(8))) short short8;  // 8 bf16 raw bits
typedef __attribute__((ext_vector_type(4))) short bf16x4;

#define B_ 2
#define T_ 256
#define D_ 2048
#define H_ 32
#define HS_ 64
#define M_ 512          // B*T
#define ST_ 66
#define EPS_ 1e-5f

__device__ __forceinline__ float bf2f(u16 u) {
    union { unsigned int i; float f; } c; c.i = ((unsigned int)u) << 16; return c.f;
}
__device__ __forceinline__ u16 f2bf(float f) {
    union { unsigned int i; float f; } c; c.f = f;
    unsigned int r = c.i + 0x7fffu + ((c.i >> 16) & 1u);   // round-to-nearest-even
    return (u16)(r >> 16);
}
__device__ __forceinline__ u16 f2bf_hw(float f) {
    __hip_bfloat16 b = __float2bfloat16(f);
    return *reinterpret_cast<u16*>(&b);
}

// ---------------- LayerNorm: x -> xln ----------------
__global__ __launch_bounds__(256) void ln_kernel(const float* __restrict__ x, const float* __restrict__ w,
                                                 const float* __restrict__ bias, float* __restrict__ xln)
{
    const int row = blockIdx.x;                 // 0..511
    const float* xr = x + (size_t)row * D_;
    float* orow = xln + (size_t)row * D_;
    const int t = threadIdx.x;
    f32x4 a0 = *(const f32x4*)(xr + t * 8);
    f32x4 a1 = *(const f32x4*)(xr + t * 8 + 4);
    float s = 0.f, q = 0.f;
#pragma unroll
    for (int i = 0; i < 4; i++) { s += a0[i] + a1[i]; q += a0[i]*a0[i] + a1[i]*a1[i]; }
#pragma unroll
    for (int off = 1; off < 64; off <<= 1) { s += __shfl_xor(s, off, 64); q += __shfl_xor(q, off, 64); }
    __shared__ float ls[4], lq[4];
    const int wid = t >> 6, lane = t & 63;
    if (lane == 0) { ls[wid] = s; lq[wid] = q; }
    __syncthreads();
    s = ls[0] + ls[1] + ls[2] + ls[3];
    q = lq[0] + lq[1] + lq[2] + lq[3];
    const float mu = s * (1.f / D_);
    const float var = q * (1.f / D_) - mu * mu;
    const float rs = rsqrtf(var + EPS_);
#pragma unroll
    for (int i = 0; i < 8; i++) {
        int d = t * 8 + i;
        float f = (i < 4) ? a0[i] : a1[i - 4];
        orow[d] = (f - mu) * rs * w[d] + bias[d];
    }
}

// ---------------- token shift: sx = prev - cur ; xxxb = bf16(xln + sx*maa_x) ----------------
__global__ __launch_bounds__(256) void shift_kernel(const float* __restrict__ xln, const float* __restrict__ state,
                                                    const float* __restrict__ maax, const int* __restrict__ ip,
                                                    float* __restrict__ sx, u16* __restrict__ xxxb)
{
    const size_t gid = (size_t)blockIdx.x * 256 + threadIdx.x;
    const size_t e = gid * 4;                   // 4 floats per thread
    const int row = (int)(e >> 11);
    const int d = (int)(e & 2047);
    const int tt = row & (T_ - 1);
    const int b = row >> 8;
    const float* prev;
    if (tt == 0) prev = state + ((size_t)b * ST_ + (size_t)(66 * ip[0] + 1)) * D_ + d;
    else         prev = xln + e - D_;
    f32x4 p = *(const f32x4*)prev;
    f32x4 c = *(const f32x4*)(xln + e);
    f32x4 mx = *(const f32x4*)(maax + d);
    f32x4 sv;
    bf16x4 xv;
#pragma unroll
    for (int i = 0; i < 4; i++) { sv[i] = p[i] - c[i]; xv[i] = (short)f2bf(c[i] + sv[i] * mx[i]); }
    *(f32x4*)(sx + e) = sv;
    *(bf16x4*)(xxxb + e) = xv;
}

// ---------------- transpose + bf16: out[n][k] = bf16(in[k][n]) ----------------
__global__ __launch_bounds__(256) void txp_kernel(const float* __restrict__ in, u16* __restrict__ out,
                                                  int K, int N)
{
    __shared__ float tile[32][33];
    const int k0 = blockIdx.x * 32, n0 = blockIdx.y * 32;
    const int c = threadIdx.x & 31, r8 = threadIdx.x >> 5;   // 0..7
#pragma unroll
    for (int i = 0; i < 4; i++) {
        int r = r8 + i * 8;
        tile[r][c] = in[(size_t)(k0 + r) * N + (n0 + c)];
    }
    __syncthreads();
#pragma unroll
    for (int i = 0; i < 4; i++) {
        int r = r8 + i * 8;
        out[(size_t)(n0 + r) * K + (k0 + c)] = f2bf(tile[c][r]);
    }
}

// ---------------- small-N MFMA GEMM: C[m,n] = act(sum_k A[m,k]*Wt[n,k]) ----------------
template<int NN, bool TANH>
__global__ __launch_bounds__(256) void gsmall_kernel(const u16* __restrict__ A, const u16* __restrict__ Wt,
                                                     float* __restrict__ C, int ldc)
{
    __shared__ u16 As[128 * 32];
    __shared__ u16 Ws[64 * 32];
    const int tid = threadIdx.x;
    const int m0 = blockIdx.y * 128, n0 = blockIdx.x * 64;
    const int lane = tid & 63, wid = tid >> 6;
    const int wm = (wid >> 1) * 64, wn = (wid & 1) * 32;

    f32x4 acc[4][2];
#pragma unroll
    for (int i = 0; i < 4; i++)
#pragma unroll
        for (int j = 0; j < 2; j++) { acc[i][j][0]=0.f; acc[i][j][1]=0.f; acc[i][j][2]=0.f; acc[i][j][3]=0.f; }

    const int rA = tid >> 2;            // 0..63
    const int kA = (tid & 3) * 8;       // 0,8,16,24
    const u16* gA0 = A + (size_t)(m0 + rA) * D_ + kA;
    const u16* gA1 = A + (size_t)(m0 + rA + 64) * D_ + kA;
    int wrow = n0 + rA; if (wrow >= NN) wrow = NN - 1;
    const u16* gW = Wt + (size_t)wrow * D_ + kA;
    u16* lA0 = As + tid * 8;
    u16* lA1 = As + (tid + 256) * 8;
    u16* lW  = Ws + tid * 8;
    const u16* pa = As + (size_t)(wm + (lane & 15)) * 32 + (lane >> 4) * 8;
    const u16* pb = Ws + (size_t)(wn + (lane & 15)) * 32 + (lane >> 4) * 8;

    short8 a0 = *(const short8*)gA0;
    short8 a1 = *(const short8*)gA1;
    short8 w0 = *(const short8*)gW;

    for (int kt = 0; kt < D_; kt += 32) {
        const int kt2 = (kt + 32) & (D_ - 1);
        short8 na0 = *(const short8*)(gA0 + kt2);
        short8 na1 = *(const short8*)(gA1 + kt2);
        short8 nw0 = *(const short8*)(gW + kt2);
        __syncthreads();
        *(short8*)lA0 = a0;
        *(short8*)lA1 = a1;
        *(short8*)lW  = w0;
        __syncthreads();
        short8 av[4], bv[2];
#pragma unroll
        for (int mi = 0; mi < 4; mi++) av[mi] = *(const short8*)(pa + mi * 16 * 32);
#pragma unroll
        for (int ni = 0; ni < 2; ni++) bv[ni] = *(const short8*)(pb + ni * 16 * 32);
#pragma unroll
        for (int mi = 0; mi < 4; mi++)
#pragma unroll
            for (int ni = 0; ni < 2; ni++)
                acc[mi][ni] = __builtin_amdgcn_mfma_f32_16x16x32_bf16(av[mi], bv[ni], acc[mi][ni], 0, 0, 0);
        a0 = na0; a1 = na1; w0 = nw0;
    }
    const int cr = wm + (lane >> 4) * 4;
    const int cc = wn + (lane & 15);
#pragma unroll
    for (int mi = 0; mi < 4; mi++)
#pragma unroll
        for (int ni = 0; ni < 2; ni++) {
            const int col = n0 + cc + ni * 16;
            if (col < NN) {
#pragma unroll
                for (int j = 0; j < 4; j++) {
                    float v = acc[mi][ni][j];
                    if (TANH) v = tanhf(v);
                    C[(size_t)(m0 + cr + mi * 16 + j) * ldc + col] = v;
                }
            }
        }
}

// ---------------- maa lora stage 2 + x5 build (bf16) ----------------
__global__ __launch_bounds__(256) void maa2_kernel(const float* __restrict__ t5, const float* __restrict__ w2,
                                                   const float* __restrict__ xln, const float* __restrict__ sxp,
                                                   const float* __restrict__ mk, const float* __restrict__ mw,
                                                   const float* __restrict__ mv, const float* __restrict__ mr,
                                                   const float* __restrict__ mg, u16* __restrict__ x5)
{
    const int gid = blockIdx.x * 256 + threadIdx.x;   // 5*2048*128
    const int d = gid & (D_ - 1);
    const int f = (gid >> 11) % 5;
    const int mg4 = gid / (5 * D_);                   // 0..127
    const float* maa = (f == 0) ? mk : (f == 1) ? mw : (f == 2) ? mv : (f == 3) ? mr : mg;
    const float mf = maa[d];
    const float* w2f = w2 + (size_t)f * 32 * D_ + d;
    const float* t5b = t5 + (size_t)mg4 * 4 * 160 + f * 32;
    float a0 = 0, a1 = 0, a2 = 0, a3 = 0;
#pragma unroll 8
    for (int r = 0; r < 32; r++) {
        float wv = w2f[(size_t)r * D_];
        a0 = fmaf(t5b[r], wv, a0);
        a1 = fmaf(t5b[160 + r], wv, a1);
        a2 = fmaf(t5b[320 + r], wv, a2);
        a3 = fmaf(t5b[480 + r], wv, a3);
    }
    const float accs[4] = {a0, a1, a2, a3};
    const size_t m0 = (size_t)mg4 * 4;
#pragma unroll
    for (int mm = 0; mm < 4; mm++) {
        size_t e = (m0 + mm) * D_ + d;
        x5[(size_t)f * M_ * D_ + e] = f2bf(xln[e] + sxp[e] * (mf + accs[mm]));
    }
}

// ---------------- decay lora stage 2: w = exp(-exp(time_decay + td @ dw2)) ----------------
__global__ __launch_bounds__(256) void decay2_kernel(const float* __restrict__ td, const float* __restrict__ dw2,
                                                     const float* __restrict__ tdec, float* __restrict__ wout)
{
    const int gid = blockIdx.x * 256 + threadIdx.x;   // 2048*128
    const int d = gid & (D_ - 1);
    const int mg4 = gid >> 11;                        // 0..127
    const float* wp = dw2 + d;
    const float* tb = td + (size_t)mg4 * 4 * 64;
    float a0 = 0, a1 = 0, a2 = 0, a3 = 0;
#pragma unroll 8
    for (int r = 0; r < 64; r++) {
        float wv = wp[(size_t)r * D_];
        a0 = fmaf(tb[r], wv, a0);
        a1 = fmaf(tb[64 + r], wv, a1);
        a2 = fmaf(tb[128 + r], wv, a2);
        a3 = fmaf(tb[192 + r], wv, a3);
    }
    const float base = tdec[d];
    const float accs[4] = {a0, a1, a2, a3};
#pragma unroll
    for (int mm = 0; mm < 4; mm++)
        wout[((size_t)mg4 * 4 + mm) * D_ + d] = expf(-expf(base + accs[mm]));
}

// ---------------- 64x64-tile bf16 MFMA GEMM, padded LDS, reg double-buffer ----------------
// C[m,n] = sum_k A[m,k] * W[n,k];  A bf16 [M][2048], W f32 [N][2048] (converted in-flight)
#define LDP_ 40   // padded row stride in u16 (2-way bank conflicts max)
__device__ __forceinline__ void gemm64_body(const u16* __restrict__ A, const float* __restrict__ W,
                                            float* __restrict__ C)
{
    __shared__ u16 As[64 * LDP_];
    __shared__ u16 Bs[64 * LDP_];
    const int tid = threadIdx.x;
    const int m0 = blockIdx.y * 64;
    const int n0 = blockIdx.x * 64;
    const int lane = tid & 63;
    const int wid = tid >> 6;
    const int wm = (wid >> 1) * 32;
    const int wn = (wid & 1) * 32;

    f32x4 acc[2][2];
#pragma unroll
    for (int i = 0; i < 2; i++)
#pragma unroll
        for (int j = 0; j < 2; j++) { acc[i][j][0]=0.f; acc[i][j][1]=0.f; acc[i][j][2]=0.f; acc[i][j][3]=0.f; }

    const int rA = tid >> 2;            // 0..63
    const int kc = (tid & 3) * 8;       // 0,8,16,24
    const u16* gA = A + (size_t)(m0 + rA) * D_ + kc;
    const float* gW = W + (size_t)(n0 + rA) * D_ + kc;
    u16* lA = As + rA * LDP_ + kc;
    u16* lB = Bs + rA * LDP_ + kc;
    const u16* pa = As + (size_t)(wm + (lane & 15)) * LDP_ + (lane >> 4) * 8;
    const u16* pb = Bs + (size_t)(wn + (lane & 15)) * LDP_ + (lane >> 4) * 8;

    short8 a0 = *(const short8*)gA;
    f32x4 w0 = *(const f32x4*)gW;
    f32x4 w1 = *(const f32x4*)(gW + 4);

    for (int kt = 0; kt < D_; kt += 32) {
        const int kt2 = (kt + 32) & (D_ - 1);   // wraps on last iter (harmless)
        short8 na = *(const short8*)(gA + kt2);
        f32x4 nw0 = *(const f32x4*)(gW + kt2);
        f32x4 nw1 = *(const f32x4*)(gW + kt2 + 4);
        __syncthreads();                 // everyone done reading previous tile
        *(short8*)lA = a0;
        short8 sb;
#pragma unroll
        for (int j = 0; j < 4; j++) {
            sb[j]     = (short)f2bf_hw(w0[j]);
            sb[j + 4] = (short)f2bf_hw(w1[j]);
        }
        *(short8*)lB = sb;
        __syncthreads();                 // tile visible
        short8 av[2], bv[2];
#pragma unroll
        for (int mi = 0; mi < 2; mi++) av[mi] = *(const short8*)(pa + mi * 16 * LDP_);
#pragma unroll
        for (int ni = 0; ni < 2; ni++) bv[ni] = *(const short8*)(pb + ni * 16 * LDP_);
#pragma unroll
        for (int mi = 0; mi < 2; mi++)
#pragma unroll
            for (int ni = 0; ni < 2; ni++)
                acc[mi][ni] = __builtin_amdgcn_mfma_f32_16x16x32_bf16(av[mi], bv[ni], acc[mi][ni], 0, 0, 0);
        a0 = na; w0 = nw0; w1 = nw1;
    }
    // epilogue: C/D layout col=lane&15, row=(lane>>4)*4+reg
    const int cr = wm + (lane >> 4) * 4;
    const int cc = wn + (lane & 15);
#pragma unroll
    for (int mi = 0; mi < 2; mi++)
#pragma unroll
        for (int ni = 0; ni < 2; ni++)
#pragma unroll
            for (int j = 0; j < 4; j++)
                C[(size_t)(m0 + cr + mi * 16 + j) * D_ + (n0 + cc + ni * 16)] = acc[mi][ni][j];
}

__global__ __launch_bounds__(256) void gemm4_kernel(const u16* __restrict__ x5, const float* __restrict__ Wk,
                                                    const float* __restrict__ Wv, const float* __restrict__ Wr,
                                                    const float* __restrict__ Wg, float* __restrict__ kvrg)
{
    const int mm = blockIdx.z;   // 0:k(x5[0]) 1:v(x5[2]) 2:r(x5[3]) 3:g(x5[4])
    const u16* A = x5 + (size_t)(mm == 0 ? 0 : mm + 1) * M_ * D_;
    const float* W = (mm == 0) ? Wk : (mm == 1) ? Wv : (mm == 2) ? Wr : Wg;
    float* C = kvrg + (size_t)mm * M_ * D_;
    gemm64_body(A, W, C);
}

__global__ __launch_bounds__(256) void gemm1_kernel(const u16* __restrict__ y, const float* __restrict__ Wo,
                                                    float* __restrict__ out)
{
    gemm64_body(y, Wo, out);
}

// ---------------- sequential recurrence over T ----------------
// 512 threads: wave wv (0..7), wg=wv>>2 picks d-half; each lane owns 8 j's x 1 d.
// chunk CH=16 staged in LDS (double-buffered); inner loop register-pipelined, barrier-free.
#define CH_ 16
__global__ __launch_bounds__(512) void rec_kernel(const float* __restrict__ rB, const float* __restrict__ kB,
                                                  const float* __restrict__ wB, const float* __restrict__ vB,
                                                  const float* __restrict__ fa, const float* __restrict__ state,
                                                  const int* __restrict__ ip, float* __restrict__ rwkv)
{
    const int bh = blockIdx.x;
    const int b = bh >> 5, h = bh & 31;
    const int tid = threadIdx.x;
    const int wv = tid >> 6, lane = tid & 63;
    const int wg = wv >> 2;
    const int jb = lane >> 3, dsub = lane & 7;
    const int jbase = jb * 8;
    const int d0 = wg * 32 + (wv & 3) * 8 + dsub;    // 0..63, each (j,d) pair exactly once

    __shared__ float stage[2][4][CH_][64];  // 32 KB
    __shared__ float p2[CH_][8][64];        // 32 KB
    __shared__ float p1[CH_][8];

    float S[8], faj[8];
    {
        const float* Sp = state + (size_t)b * ST_ * D_ + (size_t)(66 * ip[0] + 2) * D_ + (size_t)h * HS_ * HS_;
#pragma unroll
        for (int jj = 0; jj < 8; jj++) {
            S[jj]   = Sp[(jbase + jj) * 64 + d0];
            faj[jj] = fa[h * 64 + jbase + jj];
        }
    }
    const size_t base = ((size_t)b * T_ * H_ + h) * HS_;
    const int arr = wv & 3;
    const float* mysrc = (arr == 0) ? rB : (arr == 1) ? kB : (arr == 2) ? wB : vB;
    const int ts0 = wg * 8 + (lane >> 4);   // + p*4 → wave covers 8 ts of its array
    const int sch = (lane & 15) * 4;
    const bool p1w = (wv == 0 && dsub == 0);

    f32x4 pre[2];
#pragma unroll
    for (int p = 0; p < 2; p++)
        pre[p] = *(const f32x4*)(mysrc + base + (size_t)(ts0 + p * 4) * (H_ * HS_) + sch);
#pragma unroll
    for (int p = 0; p < 2; p++)
        *(f32x4*)&stage[0][arr][ts0 + p * 4][sch] = pre[p];
    __syncthreads();

    int cb = 0;
    for (int c = 0; c < T_ / CH_; ++c) {
        const bool more = (c + 1 < T_ / CH_);
        if (more) {
#pragma unroll
            for (int p = 0; p < 2; p++)
                pre[p] = *(const f32x4*)(mysrc + base + (size_t)((c + 1) * CH_ + ts0 + p * 4) * (H_ * HS_) + sch);
        }
        // register-pipelined inner loop (one ts lookahead)
        f32x4 r0 = *(const f32x4*)&stage[cb][0][0][jbase];
        f32x4 r1 = *(const f32x4*)&stage[cb][0][0][jbase + 4];
        f32x4 k0 = *(const f32x4*)&stage[cb][1][0][jbase];
        f32x4 k1 = *(const f32x4*)&stage[cb][1][0][jbase + 4];
        f32x4 w0 = *(const f32x4*)&stage[cb][2][0][jbase];
        f32x4 w1 = *(const f32x4*)&stage[cb][2][0][jbase + 4];
        float vd = stage[cb][3][0][d0];
#pragma unroll
        for (int ts = 0; ts < CH_; ++ts) {
            f32x4 nr0 = r0, nr1 = r1, nk0 = k0, nk1 = k1, nw0 = w0, nw1 = w1;
            float nvd = vd;
            if (ts + 1 < CH_) {
                nr0 = *(const f32x4*)&stage[cb][0][ts + 1][jbase];
                nr1 = *(const f32x4*)&stage[cb][0][ts + 1][jbase + 4];
                nk0 = *(const f32x4*)&stage[cb][1][ts + 1][jbase];
                nk1 = *(const f32x4*)&stage[cb][1][ts + 1][jbase + 4];
                nw0 = *(const f32x4*)&stage[cb][2][ts + 1][jbase];
                nw1 = *(const f32x4*)&stage[cb][2][ts + 1][jbase + 4];
                nvd = stage[cb][3][ts + 1][d0];
            }
            float s1 = 0.f, s2 = 0.f;
#pragma unroll
            for (int q = 0; q < 4; q++) {
                s1 = fmaf(r0[q] * faj[q],     k0[q], s1);
                s1 = fmaf(r1[q] * faj[q + 4], k1[q], s1);
                s2 = fmaf(r0[q], S[q],     s2);
                s2 = fmaf(r1[q], S[q + 4], s2);
            }
            p2[ts][jb][d0 ^ (jb << 3)] = s2;
            if (p1w) p1[ts][jb] = s1;
#pragma unroll
            for (int q = 0; q < 4; q++) {
                S[q]     = fmaf(w0[q], S[q],     k0[q] * vd);
                S[q + 4] = fmaf(w1[q], S[q + 4], k1[q] * vd);
            }
            r0 = nr0; r1 = nr1; k0 = nk0; k1 = nk1; w0 = nw0; w1 = nw1; vd = nvd;
        }
        if (more) {
#pragma unroll
            for (int p = 0; p < 2; p++)
                *(f32x4*)&stage[cb ^ 1][arr][ts0 + p * 4][sch] = pre[p];
        }
        __syncthreads();   // p2/p1 complete, next-chunk stage written
        // reduce: wave wv handles ts = wv*2 + p; lane owns output column d = lane
#pragma unroll
        for (int p = 0; p < 2; p++) {
            const int ts = wv * 2 + p;
            f32x4 p1a = *(const f32x4*)&p1[ts][0];
            f32x4 p1b = *(const f32x4*)&p1[ts][4];
            float s1t = ((p1a[0] + p1a[1]) + (p1a[2] + p1a[3])) +
                        ((p1b[0] + p1b[1]) + (p1b[2] + p1b[3]));
            float s2t = 0.f;
#pragma unroll
            for (int j = 0; j < 8; j++) s2t += p2[ts][j][lane ^ (j << 3)];
            const float vvv = stage[cb][3][ts][lane];
            rwkv[base + (size_t)(c * CH_ + ts) * (H_ * HS_) + lane] = fmaf(vvv, s1t, s2t);
        }
        __syncthreads();   // protect p2/p1 before next chunk overwrites
        cb ^= 1;
    }
}

// ---------------- groupnorm + gate: y = (gn(rwkv)*lnxw+lnxb) * silu(gpre), bf16 ----------------
__global__ __launch_bounds__(256) void gn_kernel(const float* __restrict__ rwkv, const float* __restrict__ gpre,
                                                 const float* __restrict__ lnxw, const float* __restrict__ lnxb,
                                                 u16* __restrict__ y)
{
    const int g = blockIdx.x * 4 + (threadIdx.x >> 6);   // (b*T+t)*H + h
    const int lane = threadIdx.x & 63;
    const size_t e = (size_t)g * 64 + lane;
    const float val = rwkv[e];
    float s = val, q = val * val;
#pragma unroll
    for (int off = 1; off < 64; off <<= 1) { s += __shfl_xor(s, off, 64); q += __shfl_xor(q, off, 64); }
    const float mu = s * (1.f / 64.f);
    const float var = q * (1.f / 64.f) - mu * mu;
    const float rs = rsqrtf(var + EPS_);
    const int hj = (int)(e & (size_t)(D_ - 1));
    const float nrm = (val - mu) * rs * lnxw[hj] + lnxb[hj];
    const float gp = gpre[e];
    const float gv = gp / (1.f + expf(-gp));
    y[e] = f2bf(nrm * gv);
}

extern "C" void kernel_launch(void* const* d_in, const int* in_sizes, int n_in,
                              void* d_out, int out_size, void* d_ws, size_t ws_size,
                              hipStream_t stream)
{
    const float* x     = (const float*)d_in[0];
    const float* state = (const float*)d_in[1];
    const float* ln1w  = (const float*)d_in[2];
    const float* ln1b  = (const float*)d_in[3];
    const float* maax  = (const float*)d_in[4];
    const float* w1    = (const float*)d_in[5];
    const float* w2    = (const float*)d_in[6];
    const float* maak  = (const float*)d_in[7];
    const float* maaw  = (const float*)d_in[8];
    const float* maav  = (const float*)d_in[9];
    const float* maar  = (const float*)d_in[10];
    const float* maag  = (const float*)d_in[11];
    const float* tdec  = (const float*)d_in[12];
    const float* dw1   = (const float*)d_in[13];
    const float* dw2   = (const float*)d_in[14];
    const float* fa    = (const float*)d_in[15];
    const float* wrec  = (const float*)d_in[16];
    const float* wkey  = (const float*)d_in[17];
    const float* wval  = (const float*)d_in[18];
    const float* wout  = (const float*)d_in[19];
    const float* wgate = (const float*)d_in[20];
    const float* lnxw  = (const float*)d_in[21];
    const float* lnxb  = (const float*)d_in[22];
    const int*   ip    = (const int*)d_in[23];

    char* ws = (char*)d_ws;
    const size_t MD = (size_t)M_ * D_;
    float* xln  = (float*)(ws);                          // 4 MB
    float* sx   = (float*)(ws + ((size_t)4  << 20));     // 4 MB
    u16*   xxxb = (u16*)  (ws + ((size_t)8  << 20));     // 2 MB
    u16*   w1t  = (u16*)  (ws + ((size_t)10 << 20));     // 640 KB
    u16*   dw1t = (u16*)  (ws + ((size_t)11 << 20));     // 256 KB
    float* t5   = (float*)(ws + ((size_t)12 << 20));     // 320 KB
    u16*   x5   = (u16*)  (ws + ((size_t)13 << 20));     // 10 MB
    float* td   = (float*)(ws + ((size_t)23 << 20));     // 128 KB
    float* wdec = (float*)(ws + ((size_t)24 << 20));     // 4 MB
    float* kvrg = (float*)(ws + ((size_t)28 << 20));     // 16 MB
    float* rwkv = (float*)(ws + ((size_t)44 << 20));     // 4 MB
    u16*   y    = (u16*)  (ws + ((size_t)48 << 20));     // 2 MB
    float* out  = (float*)d_out;

    hipLaunchKernelGGL(ln_kernel,     dim3(512),      dim3(256), 0, stream, x, ln1w, ln1b, xln);
    hipLaunchKernelGGL(shift_kernel,  dim3(1024),     dim3(256), 0, stream, xln, state, maax, ip, sx, xxxb);
    hipLaunchKernelGGL(txp_kernel,    dim3(64, 5),    dim3(256), 0, stream, w1, w1t, D_, 160);
    hipLaunchKernelGGL(txp_kernel,    dim3(64, 2),    dim3(256), 0, stream, dw1, dw1t, D_, 64);
    hipLaunchKernelGGL((gsmall_kernel<160, true>), dim3(3, 4), dim3(256), 0, stream, xxxb, w1t, t5, 160);
    hipLaunchKernelGGL(maa2_kernel,   dim3(5120),     dim3(256), 0, stream, t5, w2, xln, sx, maak, maaw, maav, maar, maag, x5);
    hipLaunchKernelGGL((gsmall_kernel<64, true>),  dim3(1, 4), dim3(256), 0, stream, x5 + MD, dw1t, td, 64);
    hipLaunchKernelGGL(decay2_kernel, dim3(1024),     dim3(256), 0, stream, td, dw2, tdec, wdec);
    hipLaunchKernelGGL(gemm4_kernel,  dim3(32, 8, 4), dim3(256), 0, stream, x5, wkey, wval, wrec, wgate, kvrg);
    hipLaunchKernelGGL(rec_kernel,    dim3(64),       dim3(512), 0, stream, kvrg + 2 * MD, kvrg, wdec, kvrg + MD, fa, state, ip, rwkv);
    hipLaunchKernelGGL(gn_kernel,     dim3(4096),     dim3(256), 0, stream, rwkv, kvrg + 3 * MD, lnxw, lnxb, y);
    hipLaunchKernelGGL(gemm1_kernel,  dim3(32, 8, 1), dim3(256), 0, stream, y, wout, out);

    (void)in_sizes; (void)n_in; (void)out_size; (void)ws_size;
}

// Round 7
// 203.109 us; speedup vs baseline: 2.1367x; 1.0575x over previous
//
#include <hip/hip_runtime.h>
#include <hip/hip_bf16.h>

typedef unsigned short u16;
typedef __attribute__((ext_vector_type(4))) float f32x4;
typedef __attribute__((ext_vector_type(8))) short short8;  // 8 bf16 raw bits
typedef __attribute__((ext_vector_type(4))) short bf16x4;

#define B_ 2
#define T_ 256
#define D_ 2048
#define H_ 32
#define HS_ 64
#define M_ 512          // B*T
#define ST_ 66
#define EPS_ 1e-5f

__device__ __forceinline__ float bf2f(u16 u) {
    union { unsigned int i; float f; } c; c.i = ((unsigned int)u) << 16; return c.f;
}
__device__ __forceinline__ u16 f2bf(float f) {
    union { unsigned int i; float f; } c; c.f = f;
    unsigned int r = c.i + 0x7fffu + ((c.i >> 16) & 1u);   // round-to-nearest-even
    return (u16)(r >> 16);
}
__device__ __forceinline__ u16 f2bf_hw(float f) {
    __hip_bfloat16 b = __float2bfloat16(f);
    return *reinterpret_cast<u16*>(&b);
}

// ---------------- LayerNorm: x -> xln ----------------
__global__ __launch_bounds__(256) void ln_kernel(const float* __restrict__ x, const float* __restrict__ w,
                                                 const float* __restrict__ bias, float* __restrict__ xln)
{
    const int row = blockIdx.x;                 // 0..511
    const float* xr = x + (size_t)row * D_;
    float* orow = xln + (size_t)row * D_;
    const int t = threadIdx.x;
    f32x4 a0 = *(const f32x4*)(xr + t * 8);
    f32x4 a1 = *(const f32x4*)(xr + t * 8 + 4);
    float s = 0.f, q = 0.f;
#pragma unroll
    for (int i = 0; i < 4; i++) { s += a0[i] + a1[i]; q += a0[i]*a0[i] + a1[i]*a1[i]; }
#pragma unroll
    for (int off = 1; off < 64; off <<= 1) { s += __shfl_xor(s, off, 64); q += __shfl_xor(q, off, 64); }
    __shared__ float ls[4], lq[4];
    const int wid = t >> 6, lane = t & 63;
    if (lane == 0) { ls[wid] = s; lq[wid] = q; }
    __syncthreads();
    s = ls[0] + ls[1] + ls[2] + ls[3];
    q = lq[0] + lq[1] + lq[2] + lq[3];
    const float mu = s * (1.f / D_);
    const float var = q * (1.f / D_) - mu * mu;
    const float rs = rsqrtf(var + EPS_);
#pragma unroll
    for (int i = 0; i < 8; i++) {
        int d = t * 8 + i;
        float f = (i < 4) ? a0[i] : a1[i - 4];
        orow[d] = (f - mu) * rs * w[d] + bias[d];
    }
}

// ---------------- token shift: sx = prev - cur ; xxxb = bf16(xln + sx*maa_x) ----------------
__global__ __launch_bounds__(256) void shift_kernel(const float* __restrict__ xln, const float* __restrict__ state,
                                                    const float* __restrict__ maax, const int* __restrict__ ip,
                                                    float* __restrict__ sx, u16* __restrict__ xxxb)
{
    const size_t gid = (size_t)blockIdx.x * 256 + threadIdx.x;
    const size_t e = gid * 4;                   // 4 floats per thread
    const int row = (int)(e >> 11);
    const int d = (int)(e & 2047);
    const int tt = row & (T_ - 1);
    const int b = row >> 8;
    const float* prev;
    if (tt == 0) prev = state + ((size_t)b * ST_ + (size_t)(66 * ip[0] + 1)) * D_ + d;
    else         prev = xln + e - D_;
    f32x4 p = *(const f32x4*)prev;
    f32x4 c = *(const f32x4*)(xln + e);
    f32x4 mx = *(const f32x4*)(maax + d);
    f32x4 sv;
    bf16x4 xv;
#pragma unroll
    for (int i = 0; i < 4; i++) { sv[i] = p[i] - c[i]; xv[i] = (short)f2bf(c[i] + sv[i] * mx[i]); }
    *(f32x4*)(sx + e) = sv;
    *(bf16x4*)(xxxb + e) = xv;
}

// ---------------- transpose + bf16: out[n][k] = bf16(in[k][n]) ----------------
__global__ __launch_bounds__(256) void txp_kernel(const float* __restrict__ in, u16* __restrict__ out,
                                                  int K, int N)
{
    __shared__ float tile[32][33];
    const int k0 = blockIdx.x * 32, n0 = blockIdx.y * 32;
    const int c = threadIdx.x & 31, r8 = threadIdx.x >> 5;   // 0..7
#pragma unroll
    for (int i = 0; i < 4; i++) {
        int r = r8 + i * 8;
        tile[r][c] = in[(size_t)(k0 + r) * N + (n0 + c)];
    }
    __syncthreads();
#pragma unroll
    for (int i = 0; i < 4; i++) {
        int r = r8 + i * 8;
        out[(size_t)(n0 + r) * K + (k0 + c)] = f2bf(tile[c][r]);
    }
}

// ---------------- small-N MFMA GEMM: C[m,n] = act(sum_k A[m,k]*Wt[n,k]) ----------------
template<int NN, bool TANH>
__global__ __launch_bounds__(256) void gsmall_kernel(const u16* __restrict__ A, const u16* __restrict__ Wt,
                                                     float* __restrict__ C, int ldc)
{
    __shared__ u16 As[128 * 32];
    __shared__ u16 Ws[64 * 32];
    const int tid = threadIdx.x;
    const int m0 = blockIdx.y * 128, n0 = blockIdx.x * 64;
    const int lane = tid & 63, wid = tid >> 6;
    const int wm = (wid >> 1) * 64, wn = (wid & 1) * 32;

    f32x4 acc[4][2];
#pragma unroll
    for (int i = 0; i < 4; i++)
#pragma unroll
        for (int j = 0; j < 2; j++) { acc[i][j][0]=0.f; acc[i][j][1]=0.f; acc[i][j][2]=0.f; acc[i][j][3]=0.f; }

    const int rA = tid >> 2;            // 0..63
    const int kA = (tid & 3) * 8;       // 0,8,16,24
    const u16* gA0 = A + (size_t)(m0 + rA) * D_ + kA;
    const u16* gA1 = A + (size_t)(m0 + rA + 64) * D_ + kA;
    int wrow = n0 + rA; if (wrow >= NN) wrow = NN - 1;
    const u16* gW = Wt + (size_t)wrow * D_ + kA;
    u16* lA0 = As + tid * 8;
    u16* lA1 = As + (tid + 256) * 8;
    u16* lW  = Ws + tid * 8;
    const u16* pa = As + (size_t)(wm + (lane & 15)) * 32 + (lane >> 4) * 8;
    const u16* pb = Ws + (size_t)(wn + (lane & 15)) * 32 + (lane >> 4) * 8;

    short8 a0 = *(const short8*)gA0;
    short8 a1 = *(const short8*)gA1;
    short8 w0 = *(const short8*)gW;

    for (int kt = 0; kt < D_; kt += 32) {
        const int kt2 = (kt + 32) & (D_ - 1);
        short8 na0 = *(const short8*)(gA0 + kt2);
        short8 na1 = *(const short8*)(gA1 + kt2);
        short8 nw0 = *(const short8*)(gW + kt2);
        __syncthreads();
        *(short8*)lA0 = a0;
        *(short8*)lA1 = a1;
        *(short8*)lW  = w0;
        __syncthreads();
        short8 av[4], bv[2];
#pragma unroll
        for (int mi = 0; mi < 4; mi++) av[mi] = *(const short8*)(pa + mi * 16 * 32);
#pragma unroll
        for (int ni = 0; ni < 2; ni++) bv[ni] = *(const short8*)(pb + ni * 16 * 32);
#pragma unroll
        for (int mi = 0; mi < 4; mi++)
#pragma unroll
            for (int ni = 0; ni < 2; ni++)
                acc[mi][ni] = __builtin_amdgcn_mfma_f32_16x16x32_bf16(av[mi], bv[ni], acc[mi][ni], 0, 0, 0);
        a0 = na0; a1 = na1; w0 = nw0;
    }
    const int cr = wm + (lane >> 4) * 4;
    const int cc = wn + (lane & 15);
#pragma unroll
    for (int mi = 0; mi < 4; mi++)
#pragma unroll
        for (int ni = 0; ni < 2; ni++) {
            const int col = n0 + cc + ni * 16;
            if (col < NN) {
#pragma unroll
                for (int j = 0; j < 4; j++) {
                    float v = acc[mi][ni][j];
                    if (TANH) v = tanhf(v);
                    C[(size_t)(m0 + cr + mi * 16 + j) * ldc + col] = v;
                }
            }
        }
}

// ---------------- maa lora stage 2 + x5 build (bf16) ----------------
__global__ __launch_bounds__(256) void maa2_kernel(const float* __restrict__ t5, const float* __restrict__ w2,
                                                   const float* __restrict__ xln, const float* __restrict__ sxp,
                                                   const float* __restrict__ mk, const float* __restrict__ mw,
                                                   const float* __restrict__ mv, const float* __restrict__ mr,
                                                   const float* __restrict__ mg, u16* __restrict__ x5)
{
    const int gid = blockIdx.x * 256 + threadIdx.x;   // 5*2048*128
    const int d = gid & (D_ - 1);
    const int f = (gid >> 11) % 5;
    const int mg4 = gid / (5 * D_);                   // 0..127
    const float* maa = (f == 0) ? mk : (f == 1) ? mw : (f == 2) ? mv : (f == 3) ? mr : mg;
    const float mf = maa[d];
    const float* w2f = w2 + (size_t)f * 32 * D_ + d;
    const float* t5b = t5 + (size_t)mg4 * 4 * 160 + f * 32;
    float a0 = 0, a1 = 0, a2 = 0, a3 = 0;
#pragma unroll 8
    for (int r = 0; r < 32; r++) {
        float wv = w2f[(size_t)r * D_];
        a0 = fmaf(t5b[r], wv, a0);
        a1 = fmaf(t5b[160 + r], wv, a1);
        a2 = fmaf(t5b[320 + r], wv, a2);
        a3 = fmaf(t5b[480 + r], wv, a3);
    }
    const float accs[4] = {a0, a1, a2, a3};
    const size_t m0 = (size_t)mg4 * 4;
#pragma unroll
    for (int mm = 0; mm < 4; mm++) {
        size_t e = (m0 + mm) * D_ + d;
        x5[(size_t)f * M_ * D_ + e] = f2bf(xln[e] + sxp[e] * (mf + accs[mm]));
    }
}

// ---------------- decay lora stage 2: w = exp(-exp(time_decay + td @ dw2)) ----------------
__global__ __launch_bounds__(256) void decay2_kernel(const float* __restrict__ td, const float* __restrict__ dw2,
                                                     const float* __restrict__ tdec, float* __restrict__ wout)
{
    const int gid = blockIdx.x * 256 + threadIdx.x;   // 2048*128
    const int d = gid & (D_ - 1);
    const int mg4 = gid >> 11;                        // 0..127
    const float* wp = dw2 + d;
    const float* tb = td + (size_t)mg4 * 4 * 64;
    float a0 = 0, a1 = 0, a2 = 0, a3 = 0;
#pragma unroll 8
    for (int r = 0; r < 64; r++) {
        float wv = wp[(size_t)r * D_];
        a0 = fmaf(tb[r], wv, a0);
        a1 = fmaf(tb[64 + r], wv, a1);
        a2 = fmaf(tb[128 + r], wv, a2);
        a3 = fmaf(tb[192 + r], wv, a3);
    }
    const float base = tdec[d];
    const float accs[4] = {a0, a1, a2, a3};
#pragma unroll
    for (int mm = 0; mm < 4; mm++)
        wout[((size_t)mg4 * 4 + mm) * D_ + d] = expf(-expf(base + accs[mm]));
}

// ---------------- 128x128-tile bf16 MFMA GEMM, 8 waves, depth-2 reg prefetch, split-K ----------------
// C[m,n] = sum_{k in [k0,k0+KC)} A[m,k] * W[n,k];  A bf16 [M][2048], W f32 [N][2048]
__device__ __forceinline__ void gemm128_body(const u16* __restrict__ A, const float* __restrict__ W,
                                             float* __restrict__ C, int k0, int KC)
{
    __shared__ u16 As[128 * 32];
    __shared__ u16 Bs[128 * 32];
    const int tid = threadIdx.x;          // 0..511
    const int m0 = blockIdx.y * 128;
    const int n0 = blockIdx.x * 128;
    const int lane = tid & 63;
    const int wvid = tid >> 6;            // 0..7
    const int wm = (wvid >> 1) * 32;      // 4 m-quarters
    const int wn = (wvid & 1) * 64;       // 2 n-halves

    f32x4 acc[2][4];
#pragma unroll
    for (int i = 0; i < 2; i++)
#pragma unroll
        for (int j = 0; j < 4; j++) { acc[i][j][0]=0.f; acc[i][j][1]=0.f; acc[i][j][2]=0.f; acc[i][j][3]=0.f; }

    const int rA = tid >> 2;              // 0..127
    const int kc = (tid & 3) * 8;         // 0,8,16,24
    const u16* gA = A + (size_t)(m0 + rA) * D_ + k0 + kc;
    const float* gW = W + (size_t)(n0 + rA) * D_ + k0 + kc;
    u16* lA = As + rA * 32 + kc;
    u16* lB = Bs + rA * 32 + kc;
    const u16* pa = As + (size_t)(wm + (lane & 15)) * 32 + (lane >> 4) * 8;
    const u16* pb = Bs + (size_t)(wn + (lane & 15)) * 32 + (lane >> 4) * 8;

    // depth-2 register prefetch pipeline
    short8 a0 = *(const short8*)gA;
    f32x4 w00 = *(const f32x4*)gW, w01 = *(const f32x4*)(gW + 4);
    const int kt1 = (32 < KC) ? 32 : 0;
    short8 a1 = *(const short8*)(gA + kt1);
    f32x4 w10 = *(const f32x4*)(gW + kt1), w11 = *(const f32x4*)(gW + kt1 + 4);

    for (int kt = 0; kt < KC; kt += 32) {
        const int ktn = (kt + 64 < KC) ? kt + 64 : 0;     // clamp (dummy reload, harmless)
        short8 an = *(const short8*)(gA + ktn);
        f32x4 pw0 = *(const f32x4*)(gW + ktn), pw1 = *(const f32x4*)(gW + ktn + 4);
        __syncthreads();                 // everyone done reading previous tile
        *(short8*)lA = a0;
        short8 sb;
#pragma unroll
        for (int j = 0; j < 4; j++) {
            sb[j]     = (short)f2bf_hw(w00[j]);
            sb[j + 4] = (short)f2bf_hw(w01[j]);
        }
        *(short8*)lB = sb;
        __syncthreads();                 // tile visible
        short8 av[2], bv[4];
#pragma unroll
        for (int mi = 0; mi < 2; mi++) av[mi] = *(const short8*)(pa + mi * 16 * 32);
#pragma unroll
        for (int ni = 0; ni < 4; ni++) bv[ni] = *(const short8*)(pb + ni * 16 * 32);
#pragma unroll
        for (int mi = 0; mi < 2; mi++)
#pragma unroll
            for (int ni = 0; ni < 4; ni++)
                acc[mi][ni] = __builtin_amdgcn_mfma_f32_16x16x32_bf16(av[mi], bv[ni], acc[mi][ni], 0, 0, 0);
        a0 = a1; w00 = w10; w01 = w11;
        a1 = an; w10 = pw0; w11 = pw1;
    }
    // epilogue: C/D layout col=lane&15, row=(lane>>4)*4+reg
    const int cr = wm + (lane >> 4) * 4;
    const int cc = wn + (lane & 15);
#pragma unroll
    for (int mi = 0; mi < 2; mi++)
#pragma unroll
        for (int ni = 0; ni < 4; ni++)
#pragma unroll
            for (int j = 0; j < 4; j++)
                C[(size_t)(m0 + cr + mi * 16 + j) * D_ + (n0 + cc + ni * 16)] = acc[mi][ni][j];
}

__global__ __launch_bounds__(512) void gemm4ks_kernel(const u16* __restrict__ x5, const float* __restrict__ Wk,
                                                      const float* __restrict__ Wv, const float* __restrict__ Wr,
                                                      const float* __restrict__ Wg, float* __restrict__ kvrg,
                                                      float* __restrict__ pp, int KS)
{
    const int slice = blockIdx.z / KS;    // 0:k 1:v 2:r 3:g
    const int ks = blockIdx.z - slice * KS;
    const u16* A = x5 + (size_t)(slice == 0 ? 0 : slice + 1) * M_ * D_;
    const float* W = (slice == 0) ? Wk : (slice == 1) ? Wv : (slice == 2) ? Wr : Wg;
    float* C = (ks == 0) ? kvrg + (size_t)slice * M_ * D_ : pp + (size_t)slice * M_ * D_;
    const int KC = D_ / KS;
    gemm128_body(A, W, C, ks * KC, KC);
}

__global__ __launch_bounds__(512) void gemm1ks_kernel(const u16* __restrict__ y, const float* __restrict__ Wo,
                                                      float* __restrict__ out, float* __restrict__ pp, int KS)
{
    const int ks = blockIdx.z;
    float* C = (ks == 0) ? out : pp + (size_t)(ks - 1) * M_ * D_;
    const int KC = D_ / KS;
    gemm128_body(y, Wo, C, ks * KC, KC);
}

// ---------------- split-K reduce kernels ----------------
__global__ __launch_bounds__(256) void add1_kernel(float* __restrict__ dst, const float* __restrict__ s0)
{
    const size_t e = ((size_t)blockIdx.x * 256 + threadIdx.x) * 4;
    f32x4 d = *(const f32x4*)(dst + e);
    f32x4 a = *(const f32x4*)(s0 + e);
#pragma unroll
    for (int i = 0; i < 4; i++) d[i] += a[i];
    *(f32x4*)(dst + e) = d;
}

__global__ __launch_bounds__(256) void add3_kernel(float* __restrict__ dst, const float* __restrict__ s0,
                                                   const float* __restrict__ s1, const float* __restrict__ s2)
{
    const size_t e = ((size_t)blockIdx.x * 256 + threadIdx.x) * 4;
    f32x4 d = *(const f32x4*)(dst + e);
    f32x4 a = *(const f32x4*)(s0 + e);
    f32x4 b = *(const f32x4*)(s1 + e);
    f32x4 c = *(const f32x4*)(s2 + e);
#pragma unroll
    for (int i = 0; i < 4; i++) d[i] += (a[i] + b[i]) + c[i];
    *(f32x4*)(dst + e) = d;
}

// ---------------- sequential recurrence over T ----------------
#define CH_ 16
__global__ __launch_bounds__(512) void rec_kernel(const float* __restrict__ rB, const float* __restrict__ kB,
                                                  const float* __restrict__ wB, const float* __restrict__ vB,
                                                  const float* __restrict__ fa, const float* __restrict__ state,
                                                  const int* __restrict__ ip, float* __restrict__ rwkv)
{
    const int bh = blockIdx.x;
    const int b = bh >> 5, h = bh & 31;
    const int tid = threadIdx.x;
    const int wv = tid >> 6, lane = tid & 63;
    const int wg = wv >> 2;
    const int jb = lane >> 3, dsub = lane & 7;
    const int jbase = jb * 8;
    const int d0 = wg * 32 + (wv & 3) * 8 + dsub;    // 0..63, each (j,d) pair exactly once

    __shared__ float stage[2][4][CH_][64];  // 32 KB
    __shared__ float p2[CH_][8][64];        // 32 KB
    __shared__ float p1[CH_][8];

    float S[8], faj[8];
    {
        const float* Sp = state + (size_t)b * ST_ * D_ + (size_t)(66 * ip[0] + 2) * D_ + (size_t)h * HS_ * HS_;
#pragma unroll
        for (int jj = 0; jj < 8; jj++) {
            S[jj]   = Sp[(jbase + jj) * 64 + d0];
            faj[jj] = fa[h * 64 + jbase + jj];
        }
    }
    const size_t base = ((size_t)b * T_ * H_ + h) * HS_;
    const int arr = wv & 3;
    const float* mysrc = (arr == 0) ? rB : (arr == 1) ? kB : (arr == 2) ? wB : vB;
    const int ts0 = wg * 8 + (lane >> 4);
    const int sch = (lane & 15) * 4;
    const bool p1w = (wv == 0 && dsub == 0);

    f32x4 pre[2];
#pragma unroll
    for (int p = 0; p < 2; p++)
        pre[p] = *(const f32x4*)(mysrc + base + (size_t)(ts0 + p * 4) * (H_ * HS_) + sch);
#pragma unroll
    for (int p = 0; p < 2; p++)
        *(f32x4*)&stage[0][arr][ts0 + p * 4][sch] = pre[p];
    __syncthreads();

    int cb = 0;
    for (int c = 0; c < T_ / CH_; ++c) {
        const bool more = (c + 1 < T_ / CH_);
        if (more) {
#pragma unroll
            for (int p = 0; p < 2; p++)
                pre[p] = *(const f32x4*)(mysrc + base + (size_t)((c + 1) * CH_ + ts0 + p * 4) * (H_ * HS_) + sch);
        }
        f32x4 r0 = *(const f32x4*)&stage[cb][0][0][jbase];
        f32x4 r1 = *(const f32x4*)&stage[cb][0][0][jbase + 4];
        f32x4 k0 = *(const f32x4*)&stage[cb][1][0][jbase];
        f32x4 k1 = *(const f32x4*)&stage[cb][1][0][jbase + 4];
        f32x4 w0 = *(const f32x4*)&stage[cb][2][0][jbase];
        f32x4 w1 = *(const f32x4*)&stage[cb][2][0][jbase + 4];
        float vd = stage[cb][3][0][d0];
#pragma unroll
        for (int ts = 0; ts < CH_; ++ts) {
            f32x4 nr0 = r0, nr1 = r1, nk0 = k0, nk1 = k1, nw0 = w0, nw1 = w1;
            float nvd = vd;
            if (ts + 1 < CH_) {
                nr0 = *(const f32x4*)&stage[cb][0][ts + 1][jbase];
                nr1 = *(const f32x4*)&stage[cb][0][ts + 1][jbase + 4];
                nk0 = *(const f32x4*)&stage[cb][1][ts + 1][jbase];
                nk1 = *(const f32x4*)&stage[cb][1][ts + 1][jbase + 4];
                nw0 = *(const f32x4*)&stage[cb][2][ts + 1][jbase];
                nw1 = *(const f32x4*)&stage[cb][2][ts + 1][jbase + 4];
                nvd = stage[cb][3][ts + 1][d0];
            }
            float s1 = 0.f, s2 = 0.f;
#pragma unroll
            for (int q = 0; q < 4; q++) {
                s1 = fmaf(r0[q] * faj[q],     k0[q], s1);
                s1 = fmaf(r1[q] * faj[q + 4], k1[q], s1);
                s2 = fmaf(r0[q], S[q],     s2);
                s2 = fmaf(r1[q], S[q + 4], s2);
            }
            p2[ts][jb][d0 ^ (jb << 3)] = s2;
            if (p1w) p1[ts][jb] = s1;
#pragma unroll
            for (int q = 0; q < 4; q++) {
                S[q]     = fmaf(w0[q], S[q],     k0[q] * vd);
                S[q + 4] = fmaf(w1[q], S[q + 4], k1[q] * vd);
            }
            r0 = nr0; r1 = nr1; k0 = nk0; k1 = nk1; w0 = nw0; w1 = nw1; vd = nvd;
        }
        if (more) {
#pragma unroll
            for (int p = 0; p < 2; p++)
                *(f32x4*)&stage[cb ^ 1][arr][ts0 + p * 4][sch] = pre[p];
        }
        __syncthreads();
#pragma unroll
        for (int p = 0; p < 2; p++) {
            const int ts = wv * 2 + p;
            f32x4 p1a = *(const f32x4*)&p1[ts][0];
            f32x4 p1b = *(const f32x4*)&p1[ts][4];
            float s1t = ((p1a[0] + p1a[1]) + (p1a[2] + p1a[3])) +
                        ((p1b[0] + p1b[1]) + (p1b[2] + p1b[3]));
            float s2t = 0.f;
#pragma unroll
            for (int j = 0; j < 8; j++) s2t += p2[ts][j][lane ^ (j << 3)];
            const float vvv = stage[cb][3][ts][lane];
            rwkv[base + (size_t)(c * CH_ + ts) * (H_ * HS_) + lane] = fmaf(vvv, s1t, s2t);
        }
        __syncthreads();
        cb ^= 1;
    }
}

// ---------------- groupnorm + gate: y = (gn(rwkv)*lnxw+lnxb) * silu(gpre), bf16 ----------------
__global__ __launch_bounds__(256) void gn_kernel(const float* __restrict__ rwkv, const float* __restrict__ gpre,
                                                 const float* __restrict__ lnxw, const float* __restrict__ lnxb,
                                                 u16* __restrict__ y)
{
    const int g = blockIdx.x * 4 + (threadIdx.x >> 6);   // (b*T+t)*H + h
    const int lane = threadIdx.x & 63;
    const size_t e = (size_t)g * 64 + lane;
    const float val = rwkv[e];
    float s = val, q = val * val;
#pragma unroll
    for (int off = 1; off < 64; off <<= 1) { s += __shfl_xor(s, off, 64); q += __shfl_xor(q, off, 64); }
    const float mu = s * (1.f / 64.f);
    const float var = q * (1.f / 64.f) - mu * mu;
    const float rs = rsqrtf(var + EPS_);
    const int hj = (int)(e & (size_t)(D_ - 1));
    const float nrm = (val - mu) * rs * lnxw[hj] + lnxb[hj];
    const float gp = gpre[e];
    const float gv = gp / (1.f + expf(-gp));
    y[e] = f2bf(nrm * gv);
}

extern "C" void kernel_launch(void* const* d_in, const int* in_sizes, int n_in,
                              void* d_out, int out_size, void* d_ws, size_t ws_size,
                              hipStream_t stream)
{
    const float* x     = (const float*)d_in[0];
    const float* state = (const float*)d_in[1];
    const float* ln1w  = (const float*)d_in[2];
    const float* ln1b  = (const float*)d_in[3];
    const float* maax  = (const float*)d_in[4];
    const float* w1    = (const float*)d_in[5];
    const float* w2    = (const float*)d_in[6];
    const float* maak  = (const float*)d_in[7];
    const float* maaw  = (const float*)d_in[8];
    const float* maav  = (const float*)d_in[9];
    const float* maar  = (const float*)d_in[10];
    const float* maag  = (const float*)d_in[11];
    const float* tdec  = (const float*)d_in[12];
    const float* dw1   = (const float*)d_in[13];
    const float* dw2   = (const float*)d_in[14];
    const float* fa    = (const float*)d_in[15];
    const float* wrec  = (const float*)d_in[16];
    const float* wkey  = (const float*)d_in[17];
    const float* wval  = (const float*)d_in[18];
    const float* wout  = (const float*)d_in[19];
    const float* wgate = (const float*)d_in[20];
    const float* lnxw  = (const float*)d_in[21];
    const float* lnxb  = (const float*)d_in[22];
    const int*   ip    = (const int*)d_in[23];

    char* ws = (char*)d_ws;
    const size_t MD = (size_t)M_ * D_;
    float* xln  = (float*)(ws);                          // 4 MB
    float* sx   = (float*)(ws + ((size_t)4  << 20));     // 4 MB
    u16*   xxxb = (u16*)  (ws + ((size_t)8  << 20));     // 2 MB
    u16*   w1t  = (u16*)  (ws + ((size_t)10 << 20));     // 640 KB
    u16*   dw1t = (u16*)  (ws + ((size_t)11 << 20));     // 256 KB
    float* t5   = (float*)(ws + ((size_t)12 << 20));     // 320 KB
    u16*   x5   = (u16*)  (ws + ((size_t)13 << 20));     // 10 MB
    float* td   = (float*)(ws + ((size_t)23 << 20));     // 128 KB
    float* wdec = (float*)(ws + ((size_t)24 << 20));     // 4 MB
    float* kvrg = (float*)(ws + ((size_t)28 << 20));     // 16 MB
    float* rwkv = (float*)(ws + ((size_t)44 << 20));     // 4 MB
    u16*   y    = (u16*)  (ws + ((size_t)48 << 20));     // 2 MB
    float* pp4  = (float*)(ws + ((size_t)50 << 20));     // 16 MB (split-K partials, gemm4)
    float* pp1  = (float*)(ws + ((size_t)66 << 20));     // 12 MB (split-K partials, gemm1)
    float* out  = (float*)d_out;

    const bool doks = ws_size >= ((size_t)78 << 20);
    const int KS4 = doks ? 2 : 1;
    const int KS1 = doks ? 4 : 1;

    hipLaunchKernelGGL(ln_kernel,     dim3(512),      dim3(256), 0, stream, x, ln1w, ln1b, xln);
    hipLaunchKernelGGL(shift_kernel,  dim3(1024),     dim3(256), 0, stream, xln, state, maax, ip, sx, xxxb);
    hipLaunchKernelGGL(txp_kernel,    dim3(64, 5),    dim3(256), 0, stream, w1, w1t, D_, 160);
    hipLaunchKernelGGL(txp_kernel,    dim3(64, 2),    dim3(256), 0, stream, dw1, dw1t, D_, 64);
    hipLaunchKernelGGL((gsmall_kernel<160, true>), dim3(3, 4), dim3(256), 0, stream, xxxb, w1t, t5, 160);
    hipLaunchKernelGGL(maa2_kernel,   dim3(5120),     dim3(256), 0, stream, t5, w2, xln, sx, maak, maaw, maav, maar, maag, x5);
    hipLaunchKernelGGL((gsmall_kernel<64, true>),  dim3(1, 4), dim3(256), 0, stream, x5 + MD, dw1t, td, 64);
    hipLaunchKernelGGL(decay2_kernel, dim3(1024),     dim3(256), 0, stream, td, dw2, tdec, wdec);
    hipLaunchKernelGGL(gemm4ks_kernel, dim3(16, 4, 4 * KS4), dim3(512), 0, stream, x5, wkey, wval, wrec, wgate, kvrg, pp4, KS4);
    if (doks)
        hipLaunchKernelGGL(add1_kernel, dim3(4096), dim3(256), 0, stream, kvrg, pp4);
    hipLaunchKernelGGL(rec_kernel,    dim3(64),       dim3(512), 0, stream, kvrg + 2 * MD, kvrg, wdec, kvrg + MD, fa, state, ip, rwkv);
    hipLaunchKernelGGL(gn_kernel,     dim3(4096),     dim3(256), 0, stream, rwkv, kvrg + 3 * MD, lnxw, lnxb, y);
    hipLaunchKernelGGL(gemm1ks_kernel, dim3(16, 4, KS1), dim3(512), 0, stream, y, wout, out, pp1, KS1);
    if (doks)
        hipLaunchKernelGGL(add3_kernel, dim3(1024), dim3(256), 0, stream, out, pp1, pp1 + MD, pp1 + 2 * MD);

    (void)in_sizes; (void)n_in; (void)out_size;
}